// Round 4
// baseline (943.538 us; speedup 1.0000x reference)
//
#include <hip/hip_runtime.h>
#include <cstdint>
#include <cstddef>

typedef unsigned short u16;
typedef __attribute__((ext_vector_type(4))) float f32x4;
typedef __attribute__((ext_vector_type(4))) float f4;
typedef __attribute__((ext_vector_type(8))) short short8x;
typedef __attribute__((ext_vector_type(4))) u16 u16x4;
typedef __attribute__((ext_vector_type(8))) u16 u16x8;

#define DEV static __device__ __forceinline__
#define VMC(n) asm volatile("s_waitcnt vmcnt(" #n ")" ::: "memory")
#define LG0() asm volatile("s_waitcnt lgkmcnt(0)" ::: "memory")

DEV void gl_lds16(const void* g, void* l) {
  __builtin_amdgcn_global_load_lds(
      (const __attribute__((address_space(1))) unsigned int*)g,
      (__attribute__((address_space(3))) unsigned int*)l, 16, 0, 0);
}

DEV u16 f2bf(float f) {
  unsigned u = __float_as_uint(f);
  u += 0x7fffu + ((u >> 16) & 1u);
  return (u16)(u >> 16);
}

// ---------------- cast / pack kernels ----------------

__global__ __launch_bounds__(256) void cast_bf16(const float* __restrict__ X, u16* __restrict__ Y) {
  size_t i = ((size_t)blockIdx.x * 256 + threadIdx.x) * 4;
  f4 v = *(const f4*)(X + i);
  u16x4 y;
#pragma unroll
  for (int j = 0; j < 4; ++j) y[j] = f2bf(v[j]);
  *(u16x4*)(Y + i) = y;
}

// wq [H,D,DH] f32 -> Wt [H*DH, D] bf16 (B^T form for x @ W)
__global__ __launch_bounds__(256) void cast_wqkv(const float* __restrict__ W, u16* __restrict__ Wt) {
  __shared__ float tile[64][65];
  const int t = threadIdx.x;
  const int h = blockIdx.y;
  const int d0 = blockIdx.x * 64;
  const float* Wb = W + (size_t)h * (1024 * 64);
  const int di = t >> 2;
  const int j0 = (t & 3) * 16;
#pragma unroll
  for (int c = 0; c < 4; ++c) {
    f4 v = *(const f4*)(Wb + (size_t)(d0 + di) * 64 + j0 + c * 4);
#pragma unroll
    for (int j = 0; j < 4; ++j) tile[di][j0 + c * 4 + j] = v[j];
  }
  __syncthreads();
  const int k = t >> 2;
  const int dd0 = (t & 3) * 16;
  u16x8 o0, o1;
#pragma unroll
  for (int u = 0; u < 8; ++u) o0[u] = f2bf(tile[dd0 + u][k]);
#pragma unroll
  for (int u = 0; u < 8; ++u) o1[u] = f2bf(tile[dd0 + 8 + u][k]);
  u16* dst = Wt + (size_t)(h * 64 + k) * 1024 + d0 + dd0;
  *(u16x8*)(dst) = o0;
  *(u16x8*)(dst + 8) = o1;
}

// V columns of QKV [B,S,QKVS] bf16 -> Vt [B*H, DH, S] bf16
__global__ __launch_bounds__(256) void transpose_v(const u16* __restrict__ V, u16* __restrict__ Vt,
                                                   int vstride, int voff) {
  __shared__ u16 tile[32][72];
  const int t = threadIdx.x;
  const int bh = blockIdx.y;
  const int s0 = blockIdx.x * 32;
  const u16* Vb = V + (size_t)(bh >> 4) * (1024 * (size_t)vstride) + voff + (bh & 15) * 64;
  const int si = t >> 3, d0 = (t & 7) * 8;
  u16x8 val = *(const u16x8*)(Vb + (size_t)(s0 + si) * vstride + d0);
#pragma unroll
  for (int u = 0; u < 8; ++u) tile[si][d0 + u] = val[u];
  __syncthreads();
  const int d = t >> 2, sj0 = (t & 3) * 8;
  u16x8 o;
#pragma unroll
  for (int u = 0; u < 8; ++u) o[u] = tile[sj0 + u][d];
  *(u16x8*)(Vt + (size_t)bh * (64 * 1024) + (size_t)d * 1024 + s0 + sj0) = o;
}

// ============ GEMM 256x256 tile, BK=64, 8 waves, phase-pipelined ============
// C[M,N](ldc) = A[M,K] * Bt[N,K]^T.  M,N multiples of 256, K multiple of 64 (>=192).
// EPI: 0=bf16, 1=f32, 2=bias+GELU->bf16, 3=bias->f32, 4=scale(1/8)->bf16,
//      5=fused QKV: scale cols<1024 by 1/8 -> bf16
template <int EPI>
__global__ __launch_bounds__(512, 2) void gemm256(const u16* __restrict__ A, const u16* __restrict__ Bt,
                                                  void* __restrict__ C, const float* __restrict__ bias,
                                                  int M, int N, int K, int ldc) {
  __shared__ u16 lds[65536];  // 128KB: A bufs [0,64KB), B bufs [64KB,128KB)
  char* ldsA = (char*)lds;
  char* ldsB = (char*)lds + 65536;
  const int t = threadIdx.x;
  const int wave = t >> 6, lane = t & 63;
  const int wr = wave >> 2, wc = wave & 3;
  const int lr = lane & 15, lkg = lane >> 4;
  const int swz = lr & 7;

  const int gx = gridDim.x;
  const int nwg = gx * gridDim.y;
  const int flat = blockIdx.y * gx + blockIdx.x;
  const int wg = ((nwg & 7) == 0) ? ((flat & 7) * (nwg >> 3) + (flat >> 3)) : flat;
  const int m0 = (wg / gx) * 256;
  const int n0 = (wg % gx) * 256;

  const int nk = K >> 6;
  const size_t rowb = (size_t)K * 2;

  // staging: quarter = 64 rows x 128B; thread covers (srow, swizzled chunk)
  const int srow = wave * 8 + (lane >> 3);             // 0..63
  const int sgc = ((lane & 7) ^ (srow & 7)) << 4;      // pre-swizzled global chunk
  const char* gA = (const char*)A + (size_t)(m0 + srow) * rowb + sgc;
  const char* gB = (const char*)Bt + (size_t)(n0 + srow) * rowb + sgc;

  auto stgA = [&](int kt, int q) {
    if (kt < nk)
      gl_lds16(gA + (size_t)(q * 64) * rowb + (size_t)kt * 128,
               ldsA + ((kt & 1) << 15) + (q << 13) + (wave << 10));
  };
  auto stgB = [&](int kt, int q) {
    if (kt < nk)
      gl_lds16(gB + (size_t)(q * 64) * rowb + (size_t)kt * 128,
               ldsB + ((kt & 1) << 15) + (q << 13) + (wave << 10));
  };

  const f32x4 fzero = {0.f, 0.f, 0.f, 0.f};
  f32x4 acc[8][4];
#pragma unroll
  for (int m = 0; m < 8; ++m)
#pragma unroll
    for (int n = 0; n < 4; ++n) acc[m][n] = fzero;

  // prologue: [Aq0(0),Aq2(0), Bq0..3(0), Aq1(0),Aq3(0), Aq0(1),Aq2(1)], keep newest 4
  stgA(0, 0); stgA(0, 2);
  stgB(0, 0); stgB(0, 1); stgB(0, 2); stgB(0, 3);
  stgA(0, 1); stgA(0, 3);
  stgA(1, 0); stgA(1, 2);
  VMC(4);
  __builtin_amdgcn_s_barrier();

  for (int kt = 0; kt < nk; ++kt) {
    const char* aB = ldsA + ((kt & 1) << 15);
    const char* bB = ldsB + ((kt & 1) << 15);
    short8x aF[4][2], bF[2][2];

    auto rdA = [&](int mh) {
#pragma unroll
      for (int mq = 0; mq < 4; ++mq)
#pragma unroll
        for (int kh = 0; kh < 2; ++kh)
          aF[mq][kh] = *(const short8x*)(aB + ((wr * 2 + mh) << 13) + (mq * 16 + lr) * 128 +
                                         (((kh * 4 + lkg) ^ swz) << 4));
    };
    auto rdB = [&](int nh) {
#pragma unroll
      for (int nq = 0; nq < 2; ++nq)
#pragma unroll
        for (int kh = 0; kh < 2; ++kh)
          bF[nq][kh] = *(const short8x*)(bB + (wc << 13) + (nh * 32 + nq * 16 + lr) * 128 +
                                         (((kh * 4 + lkg) ^ swz) << 4));
    };
    auto mma = [&](int mh, int nh) {
      __builtin_amdgcn_s_setprio(1);
#pragma unroll
      for (int kh = 0; kh < 2; ++kh)
#pragma unroll
        for (int mq = 0; mq < 4; ++mq)
#pragma unroll
          for (int nq = 0; nq < 2; ++nq)
            acc[mh * 4 + mq][nh * 2 + nq] = __builtin_amdgcn_mfma_f32_16x16x32_bf16(
                aF[mq][kh], bF[nq][kh], acc[mh * 4 + mq][nh * 2 + nq], 0, 0, 0);
      __builtin_amdgcn_s_setprio(0);
    };

    // ---- phase 0: quadrant (0,0) ----
    rdA(0); rdB(0);
    stgB(kt + 1, 0); stgB(kt + 1, 1);
    __builtin_amdgcn_s_barrier();
    LG0();
    mma(0, 0);
    __builtin_amdgcn_s_barrier();
    // ---- phase 1: quadrant (0,1) ----
    rdB(1);
    stgB(kt + 1, 2); stgB(kt + 1, 3);
    __builtin_amdgcn_s_barrier();
    LG0();
    mma(0, 1);
    if (kt + 1 < nk) { VMC(6); } else { VMC(0); }
    __builtin_amdgcn_s_barrier();
    // ---- phase 2: quadrant (1,0) ----
    rdA(1); rdB(0);
    stgA(kt + 1, 1); stgA(kt + 1, 3);
    stgA(kt + 2, 0); stgA(kt + 2, 2);
    __builtin_amdgcn_s_barrier();
    LG0();
    mma(1, 0);
    __builtin_amdgcn_s_barrier();
    // ---- phase 3: quadrant (1,1) ----
    rdB(1);
    __builtin_amdgcn_s_barrier();
    LG0();
    mma(1, 1);
    if (kt + 2 < nk) { VMC(4); } else if (kt + 1 < nk) { VMC(2); } else { VMC(0); }
    __builtin_amdgcn_s_barrier();
  }

  // ---- epilogue ----
#pragma unroll
  for (int m = 0; m < 8; ++m) {
#pragma unroll
    for (int rr = 0; rr < 4; ++rr) {
      const int gm = m0 + wr * 128 + m * 16 + lkg * 4 + rr;
#pragma unroll
      for (int n = 0; n < 4; ++n) {
        const int gn = n0 + wc * 64 + n * 16 + lr;
        float v = acc[m][n][rr];
        if (EPI == 2 || EPI == 3) v += bias[gn];
        if (EPI == 2) v = 0.5f * v * (1.0f + erff(v * 0.70710678118654752f));
        if (EPI == 4) v *= 0.125f;
        if (EPI == 5 && gn < 1024) v *= 0.125f;
        if (EPI == 1 || EPI == 3)
          ((float*)C)[(size_t)gm * ldc + gn] = v;
        else
          ((u16*)C)[(size_t)gm * ldc + gn] = f2bf(v);
      }
    }
  }
}

// ---------------- flash attention (R3, verified) ----------------
template <int CAUSAL>
__global__ __launch_bounds__(256, 2) void flash_attn(const u16* __restrict__ Q, const u16* __restrict__ Kk,
                                                     const u16* __restrict__ Vt, u16* __restrict__ O,
                                                     int qst) {
  __shared__ u16 Ks[2][64 * 64];
  __shared__ u16 Vs[2][64 * 64];
  __shared__ u16 Ps[4][32 * 72];
  const int t = threadIdx.x;
  const int wave = t >> 6, lane = t & 63;
  const int lr = lane & 15, lkg = lane >> 4, lk = lkg * 8;
  const int sw = lr & 7;
  const int bh = blockIdx.y;
  const size_t base = (size_t)(bh >> 4) * (1024 * (size_t)qst) + (bh & 15) * 64;
  const u16* Qb = Q + base;
  const u16* Kb = Kk + base;
  const u16* Vtb = Vt + (size_t)bh * (64 * 1024);
  u16* Ob = O + (size_t)(bh >> 4) * (1024 * 1024) + (bh & 15) * 64;
  const int qt = blockIdx.x * 128;
  const int qw = qt + wave * 32;

  const f32x4 fzero = {0.f, 0.f, 0.f, 0.f};
  short8x qf[2][2];
#pragma unroll
  for (int rb = 0; rb < 2; ++rb)
#pragma unroll
    for (int kk = 0; kk < 2; ++kk)
      qf[rb][kk] = *(const short8x*)(Qb + (size_t)(qw + rb * 16 + lr) * qst + kk * 32 + lk);

  float m_[2][4], l_[2][4];
  f32x4 o_[2][4];
#pragma unroll
  for (int rb = 0; rb < 2; ++rb) {
#pragma unroll
    for (int rr = 0; rr < 4; ++rr) { m_[rb][rr] = -1e30f; l_[rb][rr] = 0.f; }
#pragma unroll
    for (int db = 0; db < 4; ++db) o_[rb][db] = fzero;
  }

  const int rsel = lane >> 3;
  const int csw = ((lane & 7) ^ rsel) << 4;

  auto stage = [&](int buf, int kv0) {
#pragma unroll
    for (int s = 0; s < 2; ++s) {
      const int row = s * 32 + wave * 8 + rsel;
      gl_lds16((const char*)Kb + (size_t)(kv0 + row) * (size_t)(qst * 2) + csw,
               (char*)&Ks[buf][0] + s * 4096 + wave * 1024);
      gl_lds16((const char*)Vtb + (size_t)row * 2048 + (size_t)kv0 * 2 + csw,
               (char*)&Vs[buf][0] + s * 4096 + wave * 1024);
    }
  };

  const int kv_end = CAUSAL ? (qt + 128) : 1024;
  const int nt = kv_end >> 6;

  stage(0, 0);
  __syncthreads();
  int cur = 0;
  for (int tt = 0; tt < nt; ++tt) {
    const int kv0 = tt * 64;
    if (tt + 1 < nt) stage(cur ^ 1, kv0 + 64);

    const char* ksb = (const char*)&Ks[cur][0];
    const char* vsb = (const char*)&Vs[cur][0];

    short8x kf[4][2];
#pragma unroll
    for (int nb = 0; nb < 4; ++nb) {
      const int row = nb * 16 + lr;
#pragma unroll
      for (int kk = 0; kk < 2; ++kk)
        kf[nb][kk] = *(const short8x*)(ksb + row * 128 + (((kk * 4 + lkg) ^ sw) << 4));
    }

#pragma unroll
    for (int rb = 0; rb < 2; ++rb) {
      f32x4 s[4];
#pragma unroll
      for (int nb = 0; nb < 4; ++nb) {
        s[nb] = __builtin_amdgcn_mfma_f32_16x16x32_bf16(qf[rb][0], kf[nb][0], fzero, 0, 0, 0);
        s[nb] = __builtin_amdgcn_mfma_f32_16x16x32_bf16(qf[rb][1], kf[nb][1], s[nb], 0, 0, 0);
      }
      if (CAUSAL && (kv0 + 63 > qw + rb * 16)) {
#pragma unroll
        for (int rr = 0; rr < 4; ++rr) {
          const int qg = qw + rb * 16 + lkg * 4 + rr;
#pragma unroll
          for (int nb = 0; nb < 4; ++nb)
            if (kv0 + nb * 16 + lr > qg) s[nb][rr] = -1e30f;
        }
      }
#pragma unroll
      for (int rr = 0; rr < 4; ++rr) {
        float mx = fmaxf(fmaxf(s[0][rr], s[1][rr]), fmaxf(s[2][rr], s[3][rr]));
#pragma unroll
        for (int d = 1; d < 16; d <<= 1) mx = fmaxf(mx, __shfl_xor(mx, d, 16));
        const float mold = m_[rb][rr];
        const float mnew = fmaxf(mold, mx);
        float p[4];
#pragma unroll
        for (int nb = 0; nb < 4; ++nb) p[nb] = __expf(s[nb][rr] - mnew);
        float rsum = (p[0] + p[1]) + (p[2] + p[3]);
#pragma unroll
        for (int d = 1; d < 16; d <<= 1) rsum += __shfl_xor(rsum, d, 16);
        const float alpha = __expf(mold - mnew);
        m_[rb][rr] = mnew;
        l_[rb][rr] = l_[rb][rr] * alpha + rsum;
#pragma unroll
        for (int db = 0; db < 4; ++db) o_[rb][db][rr] *= alpha;
        const int prow = rb * 16 + lkg * 4 + rr;
#pragma unroll
        for (int nb = 0; nb < 4; ++nb)
          Ps[wave][prow * 72 + nb * 16 + lr] = f2bf(p[nb]);
      }
    }
    asm volatile("s_waitcnt lgkmcnt(0)" ::: "memory");

    short8x vF[4][2];
#pragma unroll
    for (int db = 0; db < 4; ++db) {
      const int row = db * 16 + lr;
#pragma unroll
      for (int kk = 0; kk < 2; ++kk)
        vF[db][kk] = *(const short8x*)(vsb + row * 128 + (((kk * 4 + lkg) ^ sw) << 4));
    }
#pragma unroll
    for (int rb = 0; rb < 2; ++rb) {
#pragma unroll
      for (int kk = 0; kk < 2; ++kk) {
        const short8x aP = *(const short8x*)((const char*)&Ps[wave][0] + (rb * 16 + lr) * 144 + kk * 64 + lkg * 16);
#pragma unroll
        for (int db = 0; db < 4; ++db)
          o_[rb][db] = __builtin_amdgcn_mfma_f32_16x16x32_bf16(aP, vF[db][kk], o_[rb][db], 0, 0, 0);
      }
    }
    __syncthreads();
    cur ^= 1;
  }

#pragma unroll
  for (int rb = 0; rb < 2; ++rb)
#pragma unroll
    for (int rr = 0; rr < 4; ++rr) {
      const float inv = 1.0f / l_[rb][rr];
      const int qg = qw + rb * 16 + lkg * 4 + rr;
#pragma unroll
      for (int db = 0; db < 4; ++db)
        Ob[(size_t)qg * 1024 + db * 16 + lr] = f2bf(o_[rb][db][rr] * inv);
    }
}

// ---------------- LayerNorm(residual) ----------------
__global__ __launch_bounds__(256) void ln_res(const float* __restrict__ X, const float* __restrict__ R,
                                              const float* __restrict__ gam, const float* __restrict__ bet,
                                              float* __restrict__ oF, u16* __restrict__ oB) {
  __shared__ float red[8];
  const int row = blockIdx.x, t = threadIdx.x;
  const int wave = t >> 6, lane = t & 63;
  const size_t off = (size_t)row * 1024 + t * 4;
  f4 x = *(const f4*)(X + off);
  f4 r = *(const f4*)(R + off);
  float v[4];
  float s = 0.f, sq = 0.f;
#pragma unroll
  for (int j = 0; j < 4; ++j) {
    v[j] = x[j] + r[j];
    s += v[j];
    sq += v[j] * v[j];
  }
#pragma unroll
  for (int d = 1; d < 64; d <<= 1) {
    s += __shfl_xor(s, d, 64);
    sq += __shfl_xor(sq, d, 64);
  }
  if (lane == 0) { red[wave * 2] = s; red[wave * 2 + 1] = sq; }
  __syncthreads();
  s = red[0] + red[2] + red[4] + red[6];
  sq = red[1] + red[3] + red[5] + red[7];
  const float mu = s * (1.0f / 1024.0f);
  const float var = sq * (1.0f / 1024.0f) - mu * mu;
  const float rs = rsqrtf(var + 1e-5f);
  f4 g4 = *(const f4*)(gam + t * 4);
  f4 b4 = *(const f4*)(bet + t * 4);
  f4 y;
#pragma unroll
  for (int j = 0; j < 4; ++j) y[j] = (v[j] - mu) * rs * g4[j] + b4[j];
  *(f4*)(oF + off) = y;
  if (oB) {
    u16x4 yb;
#pragma unroll
    for (int j = 0; j < 4; ++j) yb[j] = f2bf(y[j]);
    *(u16x4*)(oB + off) = yb;
  }
}

// ---------------- launcher ----------------
extern "C" void kernel_launch(void* const* d_in, const int* in_sizes, int n_in,
                              void* d_out, int out_size, void* d_ws, size_t ws_size,
                              hipStream_t stream) {
  const float* embeds = (const float*)d_in[0];
  const float* enc = (const float*)d_in[1];
  const float* wq1 = (const float*)d_in[2];
  const float* wk1 = (const float*)d_in[3];
  const float* wv1 = (const float*)d_in[4];
  const float* wo1 = (const float*)d_in[5];
  const float* wq2 = (const float*)d_in[6];
  const float* wk2 = (const float*)d_in[7];
  const float* wv2 = (const float*)d_in[8];
  const float* wo2 = (const float*)d_in[9];
  const float* ln1g = (const float*)d_in[10];
  const float* ln1b = (const float*)d_in[11];
  const float* ln2g = (const float*)d_in[12];
  const float* ln2b = (const float*)d_in[13];
  const float* ln3g = (const float*)d_in[14];
  const float* ln3b = (const float*)d_in[15];
  const float* w1 = (const float*)d_in[16];
  const float* b1 = (const float*)d_in[17];
  const float* w2 = (const float*)d_in[18];
  const float* b2 = (const float*)d_in[19];
  float* out = (float*)d_out;
  char* ws = (char*)d_ws;
  const size_t MB = (size_t)1 << 20;

  u16* QKV = (u16*)(ws + 0 * MB);      // 48MB [8192, 3072] bf16
  u16* Vtb = (u16*)(ws + 48 * MB);     // 16MB
  u16* Hd = (u16*)(ws + 64 * MB);      // 16MB heads
  float* Of = (float*)(ws + 80 * MB);  // 32MB f32 gemm out
  u16* ebf = (u16*)(ws + 112 * MB);    // 16MB (later reused as x1 bf16)
  u16* encb = (u16*)(ws + 128 * MB);   // 16MB (later reused as x2 bf16)
  float* x1f = (float*)(ws + 144 * MB);
  float* x2f = (float*)(ws + 176 * MB);
  u16* Wq1t = (u16*)(ws + 208 * MB);   // Wq1t/Wk1t/Wv1t contiguous = fused [3072,1024]
  u16* Wk1t = (u16*)(ws + 210 * MB);
  u16* Wv1t = (u16*)(ws + 212 * MB);
  u16* Wo1b = (u16*)(ws + 214 * MB);
  u16* Wq2t = (u16*)(ws + 216 * MB);
  u16* Wk2t = (u16*)(ws + 218 * MB);   // Wk2t/Wv2t contiguous = fused [2048,1024]
  u16* Wv2t = (u16*)(ws + 220 * MB);
  u16* Wo2b = (u16*)(ws + 222 * MB);
  u16* W1b = (u16*)(ws + 224 * MB);  // 8MB
  u16* W2b = (u16*)(ws + 232 * MB);  // 8MB, end = 240MB
  u16* x1b = ebf;
  u16* x2b = encb;
  u16* Hff = (u16*)(ws + 0 * MB);  // 64MB, reuses QKV/Vtb after attn2

  dim3 blk(256);
  dim3 blk512(512);

  cast_bf16<<<8192, blk, 0, stream>>>(embeds, ebf);
  cast_bf16<<<8192, blk, 0, stream>>>(enc, encb);
  cast_wqkv<<<dim3(16, 16), blk, 0, stream>>>(wq1, Wq1t);
  cast_wqkv<<<dim3(16, 16), blk, 0, stream>>>(wk1, Wk1t);
  cast_wqkv<<<dim3(16, 16), blk, 0, stream>>>(wv1, Wv1t);
  cast_wqkv<<<dim3(16, 16), blk, 0, stream>>>(wq2, Wq2t);
  cast_wqkv<<<dim3(16, 16), blk, 0, stream>>>(wk2, Wk2t);
  cast_wqkv<<<dim3(16, 16), blk, 0, stream>>>(wv2, Wv2t);
  cast_bf16<<<1024, blk, 0, stream>>>(wo1, Wo1b);
  cast_bf16<<<1024, blk, 0, stream>>>(wo2, Wo2b);
  cast_bf16<<<4096, blk, 0, stream>>>(w1, W1b);
  cast_bf16<<<4096, blk, 0, stream>>>(w2, W2b);

  // ---- masked self-attention + LN1 ----
  gemm256<5><<<dim3(12, 32), blk512, 0, stream>>>(ebf, Wq1t, QKV, nullptr, 8192, 3072, 1024, 3072);
  transpose_v<<<dim3(32, 128), blk, 0, stream>>>(QKV, Vtb, 3072, 2048);
  flash_attn<1><<<dim3(8, 128), blk, 0, stream>>>(QKV, QKV + 1024, Vtb, Hd, 3072);
  gemm256<1><<<dim3(4, 32), blk512, 0, stream>>>(Hd, Wo1b, Of, nullptr, 8192, 1024, 1024, 1024);
  ln_res<<<8192, blk, 0, stream>>>(Of, embeds, ln1g, ln1b, x1f, x1b);

  // ---- cross-attention + LN2 ----
  gemm256<4><<<dim3(4, 32), blk512, 0, stream>>>(x1b, Wq2t, QKV, nullptr, 8192, 1024, 1024, 3072);
  gemm256<0><<<dim3(8, 32), blk512, 0, stream>>>(encb, Wk2t, QKV + 1024, nullptr, 8192, 2048, 1024, 3072);
  transpose_v<<<dim3(32, 128), blk, 0, stream>>>(QKV, Vtb, 3072, 2048);
  flash_attn<0><<<dim3(8, 128), blk, 0, stream>>>(QKV, QKV + 1024, Vtb, Hd, 3072);
  gemm256<1><<<dim3(4, 32), blk512, 0, stream>>>(Hd, Wo2b, Of, nullptr, 8192, 1024, 1024, 1024);
  ln_res<<<8192, blk, 0, stream>>>(Of, x1f, ln2g, ln2b, x2f, x2b);

  // ---- feed-forward + LN3 ----
  gemm256<2><<<dim3(16, 32), blk512, 0, stream>>>(x2b, W1b, Hff, b1, 8192, 4096, 1024, 4096);
  gemm256<3><<<dim3(4, 32), blk512, 0, stream>>>(Hff, W2b, Of, b2, 8192, 1024, 4096, 1024);
  ln_res<<<8192, blk, 0, stream>>>(Of, x2f, ln3g, ln3b, out, nullptr);
}

// Round 5
// 905.934 us; speedup vs baseline: 1.0415x; 1.0415x over previous
//
#include <hip/hip_runtime.h>
#include <cstdint>
#include <cstddef>

typedef unsigned short u16;
typedef __attribute__((ext_vector_type(4))) float f32x4;
typedef __attribute__((ext_vector_type(4))) float f4;
typedef __attribute__((ext_vector_type(8))) short short8x;
typedef __attribute__((ext_vector_type(4))) u16 u16x4;
typedef __attribute__((ext_vector_type(8))) u16 u16x8;

#define DEV static __device__ __forceinline__
#define VMC0() asm volatile("s_waitcnt vmcnt(0)" ::: "memory")
#define LG0() asm volatile("s_waitcnt lgkmcnt(0)" ::: "memory")

DEV void gl_lds16(const void* g, void* l) {
  __builtin_amdgcn_global_load_lds(
      (const __attribute__((address_space(1))) unsigned int*)g,
      (__attribute__((address_space(3))) unsigned int*)l, 16, 0, 0);
}

DEV u16 f2bf(float f) {
  unsigned u = __float_as_uint(f);
  u += 0x7fffu + ((u >> 16) & 1u);
  return (u16)(u >> 16);
}

// ---------------- cast / pack kernels ----------------

__global__ __launch_bounds__(256) void cast_bf16(const float* __restrict__ X, u16* __restrict__ Y) {
  size_t i = ((size_t)blockIdx.x * 256 + threadIdx.x) * 4;
  f4 v = *(const f4*)(X + i);
  u16x4 y;
#pragma unroll
  for (int j = 0; j < 4; ++j) y[j] = f2bf(v[j]);
  *(u16x4*)(Y + i) = y;
}

// wq [H,D,DH] f32 -> Wt [H*DH, D] bf16 (B^T form for x @ W)
__global__ __launch_bounds__(256) void cast_wqkv(const float* __restrict__ W, u16* __restrict__ Wt) {
  __shared__ float tile[64][65];
  const int t = threadIdx.x;
  const int h = blockIdx.y;
  const int d0 = blockIdx.x * 64;
  const float* Wb = W + (size_t)h * (1024 * 64);
  const int di = t >> 2;
  const int j0 = (t & 3) * 16;
#pragma unroll
  for (int c = 0; c < 4; ++c) {
    f4 v = *(const f4*)(Wb + (size_t)(d0 + di) * 64 + j0 + c * 4);
#pragma unroll
    for (int j = 0; j < 4; ++j) tile[di][j0 + c * 4 + j] = v[j];
  }
  __syncthreads();
  const int k = t >> 2;
  const int dd0 = (t & 3) * 16;
  u16x8 o0, o1;
#pragma unroll
  for (int u = 0; u < 8; ++u) o0[u] = f2bf(tile[dd0 + u][k]);
#pragma unroll
  for (int u = 0; u < 8; ++u) o1[u] = f2bf(tile[dd0 + 8 + u][k]);
  u16* dst = Wt + (size_t)(h * 64 + k) * 1024 + d0 + dd0;
  *(u16x8*)(dst) = o0;
  *(u16x8*)(dst + 8) = o1;
}

// V columns of QKV [B,S,QKVS] bf16 -> Vt [B*H, DH, S] bf16
__global__ __launch_bounds__(256) void transpose_v(const u16* __restrict__ V, u16* __restrict__ Vt,
                                                   int vstride, int voff) {
  __shared__ u16 tile[32][72];
  const int t = threadIdx.x;
  const int bh = blockIdx.y;
  const int s0 = blockIdx.x * 32;
  const u16* Vb = V + (size_t)(bh >> 4) * (1024 * (size_t)vstride) + voff + (bh & 15) * 64;
  const int si = t >> 3, d0 = (t & 7) * 8;
  u16x8 val = *(const u16x8*)(Vb + (size_t)(s0 + si) * vstride + d0);
#pragma unroll
  for (int u = 0; u < 8; ++u) tile[si][d0 + u] = val[u];
  __syncthreads();
  const int d = t >> 2, sj0 = (t & 3) * 8;
  u16x8 o;
#pragma unroll
  for (int u = 0; u < 8; ++u) o[u] = tile[sj0 + u][d];
  *(u16x8*)(Vt + (size_t)bh * (64 * 1024) + (size_t)d * 1024 + s0 + sj0) = o;
}

// ============ GEMM BM=256 x BN tile, BK=64, 8 waves, catalog 2-phase ============
// C[M, N](ldc) = A[M,K] * Bt[N,K]^T.  M mult of 256, N mult of BN, K mult of 64.
// EPI: 0=bf16, 1=f32, 2=bias+GELU->bf16, 3=bias->f32, 4=scale(1/8)->bf16,
//      5=fused QKV: scale cols<1024 by 1/8 -> bf16
template <int EPI, int BN>
__global__ __launch_bounds__(512, 2) void gemm2ph(const u16* __restrict__ A, const u16* __restrict__ Bt,
                                                  void* __restrict__ C, const float* __restrict__ bias,
                                                  int K, int ldc) {
  constexpr int NBQ = BN / 64;          // B quarters per K-tile
  constexpr int MR = (BN == 256) ? 8 : 4;  // per-wave m-fragments
  __shared__ char ldsA[2][32768];       // 256 rows x 128B per buf
  __shared__ char ldsB[2][BN * 128];    // BN rows x 128B per buf

  const int t = threadIdx.x;
  const int wave = t >> 6, lane = t & 63;
  const int wr = (BN == 256) ? (wave >> 2) : (wave >> 1);
  const int wc = (BN == 256) ? (wave & 3) : (wave & 1);
  const int lr = lane & 15, lkg = lane >> 4;
  const int swz = lr & 7;

  const int gx = gridDim.x;
  const int nwg = gx * gridDim.y;
  const int flat = blockIdx.y * gx + blockIdx.x;
  const int wg = ((nwg & 7) == 0) ? ((flat & 7) * (nwg >> 3) + (flat >> 3)) : flat;
  const int m0 = (wg / gx) * 256;
  const int n0 = (wg % gx) * BN;

  const int nk = K >> 6;
  const size_t rowb = (size_t)K * 2;

  // staging: each gl_lds call covers 64 rows x 128B (8KB); srow/chunk pre-swizzled
  const int srow = wave * 8 + (lane >> 3);
  const int sgc = ((lane & 7) ^ (srow & 7)) << 4;
  const char* gA = (const char*)A + (size_t)(m0 + srow) * rowb + sgc;
  const char* gB = (const char*)Bt + (size_t)(n0 + srow) * rowb + sgc;

  auto stageTile = [&](int buf, int kt) {
    const size_t kb = (size_t)kt * 128;  // 64 bf16 = 128B
    char* la = &ldsA[buf][0] + (wave << 10);
    char* lb = &ldsB[buf][0] + (wave << 10);
#pragma unroll
    for (int q = 0; q < 4; ++q)
      gl_lds16(gA + (size_t)(q * 64) * rowb + kb, la + q * 8192);
#pragma unroll
    for (int q = 0; q < NBQ; ++q)
      gl_lds16(gB + (size_t)(q * 64) * rowb + kb, lb + q * 8192);
  };

  const f32x4 fzero = {0.f, 0.f, 0.f, 0.f};
  f32x4 acc[MR][4];
#pragma unroll
  for (int m = 0; m < MR; ++m)
#pragma unroll
    for (int n = 0; n < 4; ++n) acc[m][n] = fzero;

  stageTile(0, 0);
  VMC0();
  __builtin_amdgcn_s_barrier();

  int cur = 0;
  for (int kt = 0; kt < nk; ++kt) {
    if (kt + 1 < nk) stageTile(cur ^ 1, kt + 1);  // issue next-tile loads FIRST
    const char* aB = &ldsA[cur][0];
    const char* bB = &ldsB[cur][0];
#pragma unroll
    for (int kh = 0; kh < 2; ++kh) {
      short8x aF[MR], bF[4];
#pragma unroll
      for (int m = 0; m < MR; ++m) {
        const int row = wr * (MR * 16) + m * 16 + lr;
        aF[m] = *(const short8x*)(aB + row * 128 + (((kh * 4 + lkg) ^ swz) << 4));
      }
#pragma unroll
      for (int n = 0; n < 4; ++n) {
        const int row = wc * 64 + n * 16 + lr;
        bF[n] = *(const short8x*)(bB + row * 128 + (((kh * 4 + lkg) ^ swz) << 4));
      }
      LG0();
      __builtin_amdgcn_sched_barrier(0);
      __builtin_amdgcn_s_setprio(1);
#pragma unroll
      for (int m = 0; m < MR; ++m)
#pragma unroll
        for (int n = 0; n < 4; ++n)
          acc[m][n] = __builtin_amdgcn_mfma_f32_16x16x32_bf16(aF[m], bF[n], acc[m][n], 0, 0, 0);
      __builtin_amdgcn_s_setprio(0);
    }
    VMC0();                         // drain this iter's prefetch (had full compute span to land)
    __builtin_amdgcn_s_barrier();
    cur ^= 1;
  }

  // ---- epilogue ----
#pragma unroll
  for (int m = 0; m < MR; ++m) {
#pragma unroll
    for (int rr = 0; rr < 4; ++rr) {
      const int gm = m0 + wr * (MR * 16) + m * 16 + lkg * 4 + rr;
#pragma unroll
      for (int n = 0; n < 4; ++n) {
        const int gn = n0 + wc * 64 + n * 16 + lr;
        float v = acc[m][n][rr];
        if (EPI == 2 || EPI == 3) v += bias[gn];
        if (EPI == 2) v = 0.5f * v * (1.0f + erff(v * 0.70710678118654752f));
        if (EPI == 4) v *= 0.125f;
        if (EPI == 5 && gn < 1024) v *= 0.125f;
        if (EPI == 1 || EPI == 3)
          ((float*)C)[(size_t)gm * ldc + gn] = v;
        else
          ((u16*)C)[(size_t)gm * ldc + gn] = f2bf(v);
      }
    }
  }
}

// ---------------- flash attention (R3, verified) ----------------
template <int CAUSAL>
__global__ __launch_bounds__(256, 2) void flash_attn(const u16* __restrict__ Q, const u16* __restrict__ Kk,
                                                     const u16* __restrict__ Vt, u16* __restrict__ O,
                                                     int qst) {
  __shared__ u16 Ks[2][64 * 64];
  __shared__ u16 Vs[2][64 * 64];
  __shared__ u16 Ps[4][32 * 72];
  const int t = threadIdx.x;
  const int wave = t >> 6, lane = t & 63;
  const int lr = lane & 15, lkg = lane >> 4, lk = lkg * 8;
  const int sw = lr & 7;
  const int bh = blockIdx.y;
  const size_t base = (size_t)(bh >> 4) * (1024 * (size_t)qst) + (bh & 15) * 64;
  const u16* Qb = Q + base;
  const u16* Kb = Kk + base;
  const u16* Vtb = Vt + (size_t)bh * (64 * 1024);
  u16* Ob = O + (size_t)(bh >> 4) * (1024 * 1024) + (bh & 15) * 64;
  const int qt = blockIdx.x * 128;
  const int qw = qt + wave * 32;

  const f32x4 fzero = {0.f, 0.f, 0.f, 0.f};
  short8x qf[2][2];
#pragma unroll
  for (int rb = 0; rb < 2; ++rb)
#pragma unroll
    for (int kk = 0; kk < 2; ++kk)
      qf[rb][kk] = *(const short8x*)(Qb + (size_t)(qw + rb * 16 + lr) * qst + kk * 32 + lk);

  float m_[2][4], l_[2][4];
  f32x4 o_[2][4];
#pragma unroll
  for (int rb = 0; rb < 2; ++rb) {
#pragma unroll
    for (int rr = 0; rr < 4; ++rr) { m_[rb][rr] = -1e30f; l_[rb][rr] = 0.f; }
#pragma unroll
    for (int db = 0; db < 4; ++db) o_[rb][db] = fzero;
  }

  const int rsel = lane >> 3;
  const int csw = ((lane & 7) ^ rsel) << 4;

  auto stage = [&](int buf, int kv0) {
#pragma unroll
    for (int s = 0; s < 2; ++s) {
      const int row = s * 32 + wave * 8 + rsel;
      gl_lds16((const char*)Kb + (size_t)(kv0 + row) * (size_t)(qst * 2) + csw,
               (char*)&Ks[buf][0] + s * 4096 + wave * 1024);
      gl_lds16((const char*)Vtb + (size_t)row * 2048 + (size_t)kv0 * 2 + csw,
               (char*)&Vs[buf][0] + s * 4096 + wave * 1024);
    }
  };

  const int kv_end = CAUSAL ? (qt + 128) : 1024;
  const int nt = kv_end >> 6;

  stage(0, 0);
  __syncthreads();
  int cur = 0;
  for (int tt = 0; tt < nt; ++tt) {
    const int kv0 = tt * 64;
    if (tt + 1 < nt) stage(cur ^ 1, kv0 + 64);

    const char* ksb = (const char*)&Ks[cur][0];
    const char* vsb = (const char*)&Vs[cur][0];

    short8x kf[4][2];
#pragma unroll
    for (int nb = 0; nb < 4; ++nb) {
      const int row = nb * 16 + lr;
#pragma unroll
      for (int kk = 0; kk < 2; ++kk)
        kf[nb][kk] = *(const short8x*)(ksb + row * 128 + (((kk * 4 + lkg) ^ sw) << 4));
    }

#pragma unroll
    for (int rb = 0; rb < 2; ++rb) {
      f32x4 s[4];
#pragma unroll
      for (int nb = 0; nb < 4; ++nb) {
        s[nb] = __builtin_amdgcn_mfma_f32_16x16x32_bf16(qf[rb][0], kf[nb][0], fzero, 0, 0, 0);
        s[nb] = __builtin_amdgcn_mfma_f32_16x16x32_bf16(qf[rb][1], kf[nb][1], s[nb], 0, 0, 0);
      }
      if (CAUSAL && (kv0 + 63 > qw + rb * 16)) {
#pragma unroll
        for (int rr = 0; rr < 4; ++rr) {
          const int qg = qw + rb * 16 + lkg * 4 + rr;
#pragma unroll
          for (int nb = 0; nb < 4; ++nb)
            if (kv0 + nb * 16 + lr > qg) s[nb][rr] = -1e30f;
        }
      }
#pragma unroll
      for (int rr = 0; rr < 4; ++rr) {
        float mx = fmaxf(fmaxf(s[0][rr], s[1][rr]), fmaxf(s[2][rr], s[3][rr]));
#pragma unroll
        for (int d = 1; d < 16; d <<= 1) mx = fmaxf(mx, __shfl_xor(mx, d, 16));
        const float mold = m_[rb][rr];
        const float mnew = fmaxf(mold, mx);
        float p[4];
#pragma unroll
        for (int nb = 0; nb < 4; ++nb) p[nb] = __expf(s[nb][rr] - mnew);
        float rsum = (p[0] + p[1]) + (p[2] + p[3]);
#pragma unroll
        for (int d = 1; d < 16; d <<= 1) rsum += __shfl_xor(rsum, d, 16);
        const float alpha = __expf(mold - mnew);
        m_[rb][rr] = mnew;
        l_[rb][rr] = l_[rb][rr] * alpha + rsum;
#pragma unroll
        for (int db = 0; db < 4; ++db) o_[rb][db][rr] *= alpha;
        const int prow = rb * 16 + lkg * 4 + rr;
#pragma unroll
        for (int nb = 0; nb < 4; ++nb)
          Ps[wave][prow * 72 + nb * 16 + lr] = f2bf(p[nb]);
      }
    }
    asm volatile("s_waitcnt lgkmcnt(0)" ::: "memory");

    short8x vF[4][2];
#pragma unroll
    for (int db = 0; db < 4; ++db) {
      const int row = db * 16 + lr;
#pragma unroll
      for (int kk = 0; kk < 2; ++kk)
        vF[db][kk] = *(const short8x*)(vsb + row * 128 + (((kk * 4 + lkg) ^ sw) << 4));
    }
#pragma unroll
    for (int rb = 0; rb < 2; ++rb) {
#pragma unroll
      for (int kk = 0; kk < 2; ++kk) {
        const short8x aP = *(const short8x*)((const char*)&Ps[wave][0] + (rb * 16 + lr) * 144 + kk * 64 + lkg * 16);
#pragma unroll
        for (int db = 0; db < 4; ++db)
          o_[rb][db] = __builtin_amdgcn_mfma_f32_16x16x32_bf16(aP, vF[db][kk], o_[rb][db], 0, 0, 0);
      }
    }
    __syncthreads();
    cur ^= 1;
  }

#pragma unroll
  for (int rb = 0; rb < 2; ++rb)
#pragma unroll
    for (int rr = 0; rr < 4; ++rr) {
      const float inv = 1.0f / l_[rb][rr];
      const int qg = qw + rb * 16 + lkg * 4 + rr;
#pragma unroll
      for (int db = 0; db < 4; ++db)
        Ob[(size_t)qg * 1024 + db * 16 + lr] = f2bf(o_[rb][db][rr] * inv);
    }
}

// ---------------- LayerNorm(residual) ----------------
__global__ __launch_bounds__(256) void ln_res(const float* __restrict__ X, const float* __restrict__ R,
                                              const float* __restrict__ gam, const float* __restrict__ bet,
                                              float* __restrict__ oF, u16* __restrict__ oB) {
  __shared__ float red[8];
  const int row = blockIdx.x, t = threadIdx.x;
  const int wave = t >> 6, lane = t & 63;
  const size_t off = (size_t)row * 1024 + t * 4;
  f4 x = *(const f4*)(X + off);
  f4 r = *(const f4*)(R + off);
  float v[4];
  float s = 0.f, sq = 0.f;
#pragma unroll
  for (int j = 0; j < 4; ++j) {
    v[j] = x[j] + r[j];
    s += v[j];
    sq += v[j] * v[j];
  }
#pragma unroll
  for (int d = 1; d < 64; d <<= 1) {
    s += __shfl_xor(s, d, 64);
    sq += __shfl_xor(sq, d, 64);
  }
  if (lane == 0) { red[wave * 2] = s; red[wave * 2 + 1] = sq; }
  __syncthreads();
  s = red[0] + red[2] + red[4] + red[6];
  sq = red[1] + red[3] + red[5] + red[7];
  const float mu = s * (1.0f / 1024.0f);
  const float var = sq * (1.0f / 1024.0f) - mu * mu;
  const float rs = rsqrtf(var + 1e-5f);
  f4 g4 = *(const f4*)(gam + t * 4);
  f4 b4 = *(const f4*)(bet + t * 4);
  f4 y;
#pragma unroll
  for (int j = 0; j < 4; ++j) y[j] = (v[j] - mu) * rs * g4[j] + b4[j];
  *(f4*)(oF + off) = y;
  if (oB) {
    u16x4 yb;
#pragma unroll
    for (int j = 0; j < 4; ++j) yb[j] = f2bf(y[j]);
    *(u16x4*)(oB + off) = yb;
  }
}

// ---------------- launcher ----------------
extern "C" void kernel_launch(void* const* d_in, const int* in_sizes, int n_in,
                              void* d_out, int out_size, void* d_ws, size_t ws_size,
                              hipStream_t stream) {
  const float* embeds = (const float*)d_in[0];
  const float* enc = (const float*)d_in[1];
  const float* wq1 = (const float*)d_in[2];
  const float* wk1 = (const float*)d_in[3];
  const float* wv1 = (const float*)d_in[4];
  const float* wo1 = (const float*)d_in[5];
  const float* wq2 = (const float*)d_in[6];
  const float* wk2 = (const float*)d_in[7];
  const float* wv2 = (const float*)d_in[8];
  const float* wo2 = (const float*)d_in[9];
  const float* ln1g = (const float*)d_in[10];
  const float* ln1b = (const float*)d_in[11];
  const float* ln2g = (const float*)d_in[12];
  const float* ln2b = (const float*)d_in[13];
  const float* ln3g = (const float*)d_in[14];
  const float* ln3b = (const float*)d_in[15];
  const float* w1 = (const float*)d_in[16];
  const float* b1 = (const float*)d_in[17];
  const float* w2 = (const float*)d_in[18];
  const float* b2 = (const float*)d_in[19];
  float* out = (float*)d_out;
  char* ws = (char*)d_ws;
  const size_t MB = (size_t)1 << 20;

  u16* QKV = (u16*)(ws + 0 * MB);      // 48MB [8192, 3072] bf16
  u16* Vtb = (u16*)(ws + 48 * MB);     // 16MB
  u16* Hd = (u16*)(ws + 64 * MB);      // 16MB heads
  float* Of = (float*)(ws + 80 * MB);  // 32MB f32 gemm out
  u16* ebf = (u16*)(ws + 112 * MB);    // 16MB (later reused as x1 bf16)
  u16* encb = (u16*)(ws + 128 * MB);   // 16MB (later reused as x2 bf16)
  float* x1f = (float*)(ws + 144 * MB);
  float* x2f = (float*)(ws + 176 * MB);
  u16* Wq1t = (u16*)(ws + 208 * MB);   // Wq1t/Wk1t/Wv1t contiguous = fused [3072,1024]
  u16* Wk1t = (u16*)(ws + 210 * MB);
  u16* Wv1t = (u16*)(ws + 212 * MB);
  u16* Wo1b = (u16*)(ws + 214 * MB);
  u16* Wq2t = (u16*)(ws + 216 * MB);
  u16* Wk2t = (u16*)(ws + 218 * MB);   // Wk2t/Wv2t contiguous = fused [2048,1024]
  u16* Wv2t = (u16*)(ws + 220 * MB);
  u16* Wo2b = (u16*)(ws + 222 * MB);
  u16* W1b = (u16*)(ws + 224 * MB);  // 8MB
  u16* W2b = (u16*)(ws + 232 * MB);  // 8MB, end = 240MB
  u16* x1b = ebf;
  u16* x2b = encb;
  u16* Hff = (u16*)(ws + 0 * MB);  // 64MB, reuses QKV/Vtb after attn2

  dim3 blk(256);

  cast_bf16<<<8192, blk, 0, stream>>>(embeds, ebf);
  cast_bf16<<<8192, blk, 0, stream>>>(enc, encb);
  cast_wqkv<<<dim3(16, 16), blk, 0, stream>>>(wq1, Wq1t);
  cast_wqkv<<<dim3(16, 16), blk, 0, stream>>>(wk1, Wk1t);
  cast_wqkv<<<dim3(16, 16), blk, 0, stream>>>(wv1, Wv1t);
  cast_wqkv<<<dim3(16, 16), blk, 0, stream>>>(wq2, Wq2t);
  cast_wqkv<<<dim3(16, 16), blk, 0, stream>>>(wk2, Wk2t);
  cast_wqkv<<<dim3(16, 16), blk, 0, stream>>>(wv2, Wv2t);
  cast_bf16<<<1024, blk, 0, stream>>>(wo1, Wo1b);
  cast_bf16<<<1024, blk, 0, stream>>>(wo2, Wo2b);
  cast_bf16<<<4096, blk, 0, stream>>>(w1, W1b);
  cast_bf16<<<4096, blk, 0, stream>>>(w2, W2b);

  // ---- masked self-attention + LN1 ----
  gemm2ph<5, 256><<<dim3(12, 32), 512, 0, stream>>>(ebf, Wq1t, QKV, nullptr, 1024, 3072);
  transpose_v<<<dim3(32, 128), blk, 0, stream>>>(QKV, Vtb, 3072, 2048);
  flash_attn<1><<<dim3(8, 128), blk, 0, stream>>>(QKV, QKV + 1024, Vtb, Hd, 3072);
  gemm2ph<1, 128><<<dim3(8, 32), 512, 0, stream>>>(Hd, Wo1b, Of, nullptr, 1024, 1024);
  ln_res<<<8192, blk, 0, stream>>>(Of, embeds, ln1g, ln1b, x1f, x1b);

  // ---- cross-attention + LN2 ----
  gemm2ph<4, 128><<<dim3(8, 32), 512, 0, stream>>>(x1b, Wq2t, QKV, nullptr, 1024, 3072);
  gemm2ph<0, 256><<<dim3(8, 32), 512, 0, stream>>>(encb, Wk2t, QKV + 1024, nullptr, 1024, 3072);
  transpose_v<<<dim3(32, 128), blk, 0, stream>>>(QKV, Vtb, 3072, 2048);
  flash_attn<0><<<dim3(8, 128), blk, 0, stream>>>(QKV, QKV + 1024, Vtb, Hd, 3072);
  gemm2ph<1, 128><<<dim3(8, 32), 512, 0, stream>>>(Hd, Wo2b, Of, nullptr, 1024, 1024);
  ln_res<<<8192, blk, 0, stream>>>(Of, x1f, ln2g, ln2b, x2f, x2b);

  // ---- feed-forward + LN3 ----
  gemm2ph<2, 256><<<dim3(16, 32), 512, 0, stream>>>(x2b, W1b, Hff, b1, 1024, 4096);
  gemm2ph<3, 128><<<dim3(8, 32), 512, 0, stream>>>(Hff, W2b, Of, b2, 4096, 1024);
  ln_res<<<8192, blk, 0, stream>>>(Of, x2f, ln3g, ln3b, out, nullptr);
}

// Round 6
// 872.564 us; speedup vs baseline: 1.0813x; 1.0382x over previous
//
#include <hip/hip_runtime.h>
#include <cstdint>
#include <cstddef>

typedef unsigned short u16;
typedef __attribute__((ext_vector_type(4))) float f32x4;
typedef __attribute__((ext_vector_type(4))) float f4;
typedef __attribute__((ext_vector_type(8))) short short8x;
typedef __attribute__((ext_vector_type(4))) u16 u16x4;
typedef __attribute__((ext_vector_type(8))) u16 u16x8;

#define DEV static __device__ __forceinline__
#define VMC(n) asm volatile("s_waitcnt vmcnt(" #n ")" ::: "memory")
#define LG0() asm volatile("s_waitcnt lgkmcnt(0)" ::: "memory")

DEV void gl_lds16(const void* g, void* l) {
  __builtin_amdgcn_global_load_lds(
      (const __attribute__((address_space(1))) unsigned int*)g,
      (__attribute__((address_space(3))) unsigned int*)l, 16, 0, 0);
}

DEV u16 f2bf(float f) {
  unsigned u = __float_as_uint(f);
  u += 0x7fffu + ((u >> 16) & 1u);
  return (u16)(u >> 16);
}

// ---------------- cast / pack kernels ----------------

__global__ __launch_bounds__(256) void cast_bf16(const float* __restrict__ X, u16* __restrict__ Y) {
  size_t i = ((size_t)blockIdx.x * 256 + threadIdx.x) * 4;
  f4 v = *(const f4*)(X + i);
  u16x4 y;
#pragma unroll
  for (int j = 0; j < 4; ++j) y[j] = f2bf(v[j]);
  *(u16x4*)(Y + i) = y;
}

// wq [H,D,DH] f32 -> Wt [H*DH, D] bf16 (B^T form for x @ W)
__global__ __launch_bounds__(256) void cast_wqkv(const float* __restrict__ W, u16* __restrict__ Wt) {
  __shared__ float tile[64][65];
  const int t = threadIdx.x;
  const int h = blockIdx.y;
  const int d0 = blockIdx.x * 64;
  const float* Wb = W + (size_t)h * (1024 * 64);
  const int di = t >> 2;
  const int j0 = (t & 3) * 16;
#pragma unroll
  for (int c = 0; c < 4; ++c) {
    f4 v = *(const f4*)(Wb + (size_t)(d0 + di) * 64 + j0 + c * 4);
#pragma unroll
    for (int j = 0; j < 4; ++j) tile[di][j0 + c * 4 + j] = v[j];
  }
  __syncthreads();
  const int k = t >> 2;
  const int dd0 = (t & 3) * 16;
  u16x8 o0, o1;
#pragma unroll
  for (int u = 0; u < 8; ++u) o0[u] = f2bf(tile[dd0 + u][k]);
#pragma unroll
  for (int u = 0; u < 8; ++u) o1[u] = f2bf(tile[dd0 + 8 + u][k]);
  u16* dst = Wt + (size_t)(h * 64 + k) * 1024 + d0 + dd0;
  *(u16x8*)(dst) = o0;
  *(u16x8*)(dst + 8) = o1;
}

// V columns of QKV [B,S,QKVS] bf16 -> Vt [B*H, DH, S] bf16
__global__ __launch_bounds__(256) void transpose_v(const u16* __restrict__ V, u16* __restrict__ Vt,
                                                   int vstride, int voff) {
  __shared__ u16 tile[32][72];
  const int t = threadIdx.x;
  const int bh = blockIdx.y;
  const int s0 = blockIdx.x * 32;
  const u16* Vb = V + (size_t)(bh >> 4) * (1024 * (size_t)vstride) + voff + (bh & 15) * 64;
  const int si = t >> 3, d0 = (t & 7) * 8;
  u16x8 val = *(const u16x8*)(Vb + (size_t)(s0 + si) * vstride + d0);
#pragma unroll
  for (int u = 0; u < 8; ++u) tile[si][d0 + u] = val[u];
  __syncthreads();
  const int d = t >> 2, sj0 = (t & 3) * 8;
  u16x8 o;
#pragma unroll
  for (int u = 0; u < 8; ++u) o[u] = tile[sj0 + u][d];
  *(u16x8*)(Vt + (size_t)bh * (64 * 1024) + (size_t)d * 1024 + s0 + sj0) = o;
}

// ======== GEMM 256x256, BK=64, 8 waves, m201-style 8-phase counted-vmcnt ========
// C[M,N](ldc) = A[M,K]*Bt[N,K]^T, K-chunk per blockIdx.z (column offset z*Ksub).
// EPI: 0=bf16, 1=f32, 2=bias+GELU->bf16, 5=fused QKV scale cols<1024 by 1/8 ->bf16
#define MMA_PHASE(MH, NH, BF)                                                      \
  {                                                                                \
    __builtin_amdgcn_s_setprio(1);                                                 \
    _Pragma("unroll") for (int kh = 0; kh < 2; ++kh)                               \
        _Pragma("unroll") for (int mq = 0; mq < 4; ++mq)                           \
            _Pragma("unroll") for (int nq = 0; nq < 2; ++nq)                       \
                acc[(MH)*4 + mq][(NH)*2 + nq] =                                    \
                    __builtin_amdgcn_mfma_f32_16x16x32_bf16(                       \
                        aF[mq][kh], BF[nq][kh], acc[(MH)*4 + mq][(NH)*2 + nq],     \
                        0, 0, 0);                                                  \
    __builtin_amdgcn_s_setprio(0);                                                 \
  }

template <int EPI>
__global__ __launch_bounds__(512, 2) void gemm8(const u16* __restrict__ A, int lda,
                                                const u16* __restrict__ Bt, int ldb,
                                                void* __restrict__ C, int ldc,
                                                const float* __restrict__ bias,
                                                int Ksub, long long zCoff) {
  __shared__ char ldsA[65536];  // 2 dbuf x 2 half x (128 rows x 128B)
  __shared__ char ldsB[65536];
  const int t = threadIdx.x;
  const int wave = t >> 6, lane = t & 63;
  const int wr = wave >> 2, wc = wave & 3;
  const int lr = lane & 15, lkg = lane >> 4;
  const int swz = lr & 7;

  const int gx = gridDim.x;
  const int nwg = gx * gridDim.y;
  const int flat = blockIdx.y * gx + blockIdx.x;
  const int wg = (flat & 7) * (nwg >> 3) + (flat >> 3);  // all grids %8==0
  const int m0 = (wg / gx) * 256;
  const int n0 = (wg % gx) * 256;

  const int nk = Ksub >> 6;
  const size_t rowbA = (size_t)lda * 2, rowbB = (size_t)ldb * 2;
  const size_t kz = (size_t)blockIdx.z * (size_t)Ksub * 2;

  const int srow8 = wave * 8 + (lane >> 3);
  const int sgc = ((lane & 7) ^ ((lane >> 3) & 7)) << 4;
  const char* gA = (const char*)A + kz + sgc;
  const char* gB = (const char*)Bt + kz + sgc;

  // A half h rows: {h*64+0..63} u {h*64+128..191}; B half h rows: 4 chunks of 32.
  auto stgA = [&](int kt, int h) {
    if (kt >= nk) return;
    char* dst = ldsA + ((kt & 1) << 15) + (h << 14) + (wave << 10);
#pragma unroll
    for (int L = 0; L < 2; ++L)
      gl_lds16(gA + (size_t)(m0 + h * 64 + L * 128 + srow8) * rowbA + (size_t)kt * 128,
               dst + L * 8192);
  };
  auto stgB = [&](int kt, int h) {
    if (kt >= nk) return;
    char* dst = ldsB + ((kt & 1) << 15) + (h << 14) + (wave << 10);
#pragma unroll
    for (int L = 0; L < 2; ++L) {
      const int grow = n0 + (L * 2 + (wave >> 2)) * 64 + h * 32 + (wave & 3) * 8 + (lane >> 3);
      gl_lds16(gB + (size_t)grow * rowbB + (size_t)kt * 128, dst + L * 8192);
    }
  };

  short8x aF[4][2], bF0[2][2], bF1[2][2];
  auto rdA = [&](int b, int mh) {
    const char* base = ldsA + (b << 15) + (mh << 14);
#pragma unroll
    for (int mq = 0; mq < 4; ++mq)
#pragma unroll
      for (int kh = 0; kh < 2; ++kh)
        aF[mq][kh] = *(const short8x*)(base + (wr * 64 + mq * 16 + lr) * 128 +
                                       (((kh * 4 + lkg) ^ swz) << 4));
  };
  auto rdB = [&](int b, int nh, short8x(&bF)[2][2]) {
    const char* base = ldsB + (b << 15) + (nh << 14);
#pragma unroll
    for (int nq = 0; nq < 2; ++nq)
#pragma unroll
      for (int kh = 0; kh < 2; ++kh)
        bF[nq][kh] = *(const short8x*)(base + (wc * 32 + nq * 16 + lr) * 128 +
                                       (((kh * 4 + lkg) ^ swz) << 4));
  };

  const f32x4 fzero = {0.f, 0.f, 0.f, 0.f};
  f32x4 acc[8][4];
#pragma unroll
  for (int m = 0; m < 8; ++m)
#pragma unroll
    for (int n = 0; n < 4; ++n) acc[m][n] = fzero;

  // prologue: tile0 (4 halves) -> vmcnt(4); +3 halves of tile1 -> vmcnt(6)
  stgA(0, 0); stgB(0, 0); stgB(0, 1); stgA(0, 1);
  VMC(4);
  stgA(1, 0); stgB(1, 0); stgB(1, 1);
  VMC(6);
  __builtin_amdgcn_s_barrier();

  for (int kt = 0; kt < nk; ++kt) {
    const int b = kt & 1;
    // ---- phase 0: (mh0, nh0) ----
    rdA(b, 0); rdB(b, 0, bF0);
    stgA(kt + 1, 1);
    __builtin_amdgcn_s_barrier();
    LG0(); __builtin_amdgcn_sched_barrier(0);
    MMA_PHASE(0, 0, bF0);
    __builtin_amdgcn_s_barrier();
    // ---- phase 1: (mh0, nh1) ----
    rdB(b, 1, bF1);
    stgA(kt + 2, 0);
    __builtin_amdgcn_s_barrier();
    LG0(); __builtin_amdgcn_sched_barrier(0);
    MMA_PHASE(0, 1, bF1);
    __builtin_amdgcn_s_barrier();
    // ---- phase 2: (mh1, nh0) ----
    rdA(b, 1);
    stgB(kt + 2, 0);
    __builtin_amdgcn_s_barrier();
    LG0(); __builtin_amdgcn_sched_barrier(0);
    MMA_PHASE(1, 0, bF0);
    __builtin_amdgcn_s_barrier();
    // ---- phase 3: (mh1, nh1) ----
    stgB(kt + 2, 1);
    __builtin_amdgcn_s_barrier();
    MMA_PHASE(1, 1, bF1);
    if (kt + 2 < nk) { VMC(6); } else { VMC(0); }
    __builtin_amdgcn_s_barrier();
  }

  // ---- epilogue ----
#pragma unroll
  for (int m = 0; m < 8; ++m) {
#pragma unroll
    for (int rr = 0; rr < 4; ++rr) {
      const int gm = m0 + wr * 128 + (m >> 2) * 64 + (m & 3) * 16 + lkg * 4 + rr;
#pragma unroll
      for (int n = 0; n < 4; ++n) {
        const int gn = n0 + wc * 64 + (n >> 1) * 32 + (n & 1) * 16 + lr;
        float v = acc[m][n][rr];
        if (EPI == 2) {
          v += bias[gn];
          v = 0.5f * v * (1.0f + erff(v * 0.70710678118654752f));
        }
        if (EPI == 5 && gn < 1024) v *= 0.125f;
        if (EPI == 1)
          ((float*)C)[(size_t)blockIdx.z * zCoff + (size_t)gm * ldc + gn] = v;
        else
          ((u16*)C)[(size_t)gm * ldc + gn] = f2bf(v);
      }
    }
  }
}

// -------- GEMM 128x128 2-phase (R2-verified, 0 conflicts) for small-N --------
// EPI: 1=f32, 4=scale(1/8)->bf16
template <int EPI>
__global__ __launch_bounds__(256, 3) void gemm_bt(const u16* __restrict__ A, const u16* __restrict__ Bt,
                                                  void* __restrict__ C, int N, int K, int ldc) {
  __shared__ u16 As[2][128 * 32];
  __shared__ u16 Bs[2][128 * 32];
  const int t = threadIdx.x;
  const int wave = t >> 6, lane = t & 63;
  const int lr = lane & 15, lkg = lane >> 4;
  const int swz = (lr >> 1) & 3;
  const int wr = (wave >> 1) * 64, wc = (wave & 1) * 64;
  const int m0 = blockIdx.y * 128, n0 = blockIdx.x * 128;

  const int schunk = ((t & 3) ^ ((t >> 3) & 3)) << 4;
  const char* gA = (const char*)(A + (size_t)(m0 + (t >> 2)) * K) + schunk;
  const char* gB = (const char*)(Bt + (size_t)(n0 + (t >> 2)) * K) + schunk;
  const size_t rowskip = (size_t)64 * K * 2;

  const f32x4 fzero = {0.f, 0.f, 0.f, 0.f};
  f32x4 acc[4][4];
#pragma unroll
  for (int m = 0; m < 4; ++m)
#pragma unroll
    for (int n = 0; n < 4; ++n) acc[m][n] = fzero;

  const int nk = K >> 5;

  auto stage = [&](int buf, int kt) {
    const size_t kb = (size_t)kt * 64;
    char* la = ((char*)&As[buf][0]) + wave * 1024;
    char* lb = ((char*)&Bs[buf][0]) + wave * 1024;
    gl_lds16(gA + kb, la);
    gl_lds16(gA + kb + rowskip, la + 4096);
    gl_lds16(gB + kb, lb);
    gl_lds16(gB + kb + rowskip, lb + 4096);
  };

  auto compute = [&](int buf) {
    const char* as = (const char*)&As[buf][0];
    const char* bs = (const char*)&Bs[buf][0];
    short8x aF[4], bF[4];
#pragma unroll
    for (int m = 0; m < 4; ++m)
      aF[m] = *(const short8x*)(as + (size_t)(wr + m * 16 + lr) * 64 + ((lkg ^ swz) << 4));
#pragma unroll
    for (int n = 0; n < 4; ++n)
      bF[n] = *(const short8x*)(bs + (size_t)(wc + n * 16 + lr) * 64 + ((lkg ^ swz) << 4));
#pragma unroll
    for (int m = 0; m < 4; ++m)
#pragma unroll
      for (int n = 0; n < 4; ++n)
        acc[m][n] = __builtin_amdgcn_mfma_f32_16x16x32_bf16(aF[m], bF[n], acc[m][n], 0, 0, 0);
  };

  stage(0, 0);
  __syncthreads();
  int cur = 0;
  for (int kt = 0; kt < nk; ++kt) {
    if (kt + 1 < nk) stage(cur ^ 1, kt + 1);
    compute(cur);
    __syncthreads();
    cur ^= 1;
  }

#pragma unroll
  for (int m = 0; m < 4; ++m) {
#pragma unroll
    for (int rr = 0; rr < 4; ++rr) {
      const int gm = m0 + wr + m * 16 + lkg * 4 + rr;
#pragma unroll
      for (int n = 0; n < 4; ++n) {
        const int gn = n0 + wc + n * 16 + lr;
        float v = acc[m][n][rr];
        if (EPI == 4) v *= 0.125f;
        if (EPI == 1)
          ((float*)C)[(size_t)gm * ldc + gn] = v;
        else
          ((u16*)C)[(size_t)gm * ldc + gn] = f2bf(v);
      }
    }
  }
}

// ---------------- flash attention (verified) ----------------
template <int CAUSAL>
__global__ __launch_bounds__(256, 2) void flash_attn(const u16* __restrict__ Q, const u16* __restrict__ Kk,
                                                     const u16* __restrict__ Vt, u16* __restrict__ O,
                                                     int qst) {
  __shared__ u16 Ks[2][64 * 64];
  __shared__ u16 Vs[2][64 * 64];
  __shared__ u16 Ps[4][32 * 72];
  const int t = threadIdx.x;
  const int wave = t >> 6, lane = t & 63;
  const int lr = lane & 15, lkg = lane >> 4, lk = lkg * 8;
  const int sw = lr & 7;
  const int bh = blockIdx.y;
  const size_t base = (size_t)(bh >> 4) * (1024 * (size_t)qst) + (bh & 15) * 64;
  const u16* Qb = Q + base;
  const u16* Kb = Kk + base;
  const u16* Vtb = Vt + (size_t)bh * (64 * 1024);
  u16* Ob = O + (size_t)(bh >> 4) * (1024 * 1024) + (bh & 15) * 64;
  const int qt = blockIdx.x * 128;
  const int qw = qt + wave * 32;

  const f32x4 fzero = {0.f, 0.f, 0.f, 0.f};
  short8x qf[2][2];
#pragma unroll
  for (int rb = 0; rb < 2; ++rb)
#pragma unroll
    for (int kk = 0; kk < 2; ++kk)
      qf[rb][kk] = *(const short8x*)(Qb + (size_t)(qw + rb * 16 + lr) * qst + kk * 32 + lk);

  float m_[2][4], l_[2][4];
  f32x4 o_[2][4];
#pragma unroll
  for (int rb = 0; rb < 2; ++rb) {
#pragma unroll
    for (int rr = 0; rr < 4; ++rr) { m_[rb][rr] = -1e30f; l_[rb][rr] = 0.f; }
#pragma unroll
    for (int db = 0; db < 4; ++db) o_[rb][db] = fzero;
  }

  const int rsel = lane >> 3;
  const int csw = ((lane & 7) ^ rsel) << 4;

  auto stage = [&](int buf, int kv0) {
#pragma unroll
    for (int s = 0; s < 2; ++s) {
      const int row = s * 32 + wave * 8 + rsel;
      gl_lds16((const char*)Kb + (size_t)(kv0 + row) * (size_t)(qst * 2) + csw,
               (char*)&Ks[buf][0] + s * 4096 + wave * 1024);
      gl_lds16((const char*)Vtb + (size_t)row * 2048 + (size_t)kv0 * 2 + csw,
               (char*)&Vs[buf][0] + s * 4096 + wave * 1024);
    }
  };

  const int kv_end = CAUSAL ? (qt + 128) : 1024;
  const int nt = kv_end >> 6;

  stage(0, 0);
  __syncthreads();
  int cur = 0;
  for (int tt = 0; tt < nt; ++tt) {
    const int kv0 = tt * 64;
    if (tt + 1 < nt) stage(cur ^ 1, kv0 + 64);

    const char* ksb = (const char*)&Ks[cur][0];
    const char* vsb = (const char*)&Vs[cur][0];

    short8x kf[4][2];
#pragma unroll
    for (int nb = 0; nb < 4; ++nb) {
      const int row = nb * 16 + lr;
#pragma unroll
      for (int kk = 0; kk < 2; ++kk)
        kf[nb][kk] = *(const short8x*)(ksb + row * 128 + (((kk * 4 + lkg) ^ sw) << 4));
    }

#pragma unroll
    for (int rb = 0; rb < 2; ++rb) {
      f32x4 s[4];
#pragma unroll
      for (int nb = 0; nb < 4; ++nb) {
        s[nb] = __builtin_amdgcn_mfma_f32_16x16x32_bf16(qf[rb][0], kf[nb][0], fzero, 0, 0, 0);
        s[nb] = __builtin_amdgcn_mfma_f32_16x16x32_bf16(qf[rb][1], kf[nb][1], s[nb], 0, 0, 0);
      }
      if (CAUSAL && (kv0 + 63 > qw + rb * 16)) {
#pragma unroll
        for (int rr = 0; rr < 4; ++rr) {
          const int qg = qw + rb * 16 + lkg * 4 + rr;
#pragma unroll
          for (int nb = 0; nb < 4; ++nb)
            if (kv0 + nb * 16 + lr > qg) s[nb][rr] = -1e30f;
        }
      }
#pragma unroll
      for (int rr = 0; rr < 4; ++rr) {
        float mx = fmaxf(fmaxf(s[0][rr], s[1][rr]), fmaxf(s[2][rr], s[3][rr]));
#pragma unroll
        for (int d = 1; d < 16; d <<= 1) mx = fmaxf(mx, __shfl_xor(mx, d, 16));
        const float mold = m_[rb][rr];
        const float mnew = fmaxf(mold, mx);
        float p[4];
#pragma unroll
        for (int nb = 0; nb < 4; ++nb) p[nb] = __expf(s[nb][rr] - mnew);
        float rsum = (p[0] + p[1]) + (p[2] + p[3]);
#pragma unroll
        for (int d = 1; d < 16; d <<= 1) rsum += __shfl_xor(rsum, d, 16);
        const float alpha = __expf(mold - mnew);
        m_[rb][rr] = mnew;
        l_[rb][rr] = l_[rb][rr] * alpha + rsum;
#pragma unroll
        for (int db = 0; db < 4; ++db) o_[rb][db][rr] *= alpha;
        const int prow = rb * 16 + lkg * 4 + rr;
#pragma unroll
        for (int nb = 0; nb < 4; ++nb)
          Ps[wave][prow * 72 + nb * 16 + lr] = f2bf(p[nb]);
      }
    }
    asm volatile("s_waitcnt lgkmcnt(0)" ::: "memory");

    short8x vF[4][2];
#pragma unroll
    for (int db = 0; db < 4; ++db) {
      const int row = db * 16 + lr;
#pragma unroll
      for (int kk = 0; kk < 2; ++kk)
        vF[db][kk] = *(const short8x*)(vsb + row * 128 + (((kk * 4 + lkg) ^ sw) << 4));
    }
#pragma unroll
    for (int rb = 0; rb < 2; ++rb) {
#pragma unroll
      for (int kk = 0; kk < 2; ++kk) {
        const short8x aP = *(const short8x*)((const char*)&Ps[wave][0] + (rb * 16 + lr) * 144 + kk * 64 + lkg * 16);
#pragma unroll
        for (int db = 0; db < 4; ++db)
          o_[rb][db] = __builtin_amdgcn_mfma_f32_16x16x32_bf16(aP, vF[db][kk], o_[rb][db], 0, 0, 0);
      }
    }
    __syncthreads();
    cur ^= 1;
  }

#pragma unroll
  for (int rb = 0; rb < 2; ++rb)
#pragma unroll
    for (int rr = 0; rr < 4; ++rr) {
      const float inv = 1.0f / l_[rb][rr];
      const int qg = qw + rb * 16 + lkg * 4 + rr;
#pragma unroll
      for (int db = 0; db < 4; ++db)
        Ob[(size_t)qg * 1024 + db * 16 + lr] = f2bf(o_[rb][db][rr] * inv);
    }
}

// ---------------- LayerNorm(X [+X2] [+bias] + R) ----------------
__global__ __launch_bounds__(256) void ln_res(const float* __restrict__ X, const float* __restrict__ X2,
                                              const float* __restrict__ bias, const float* __restrict__ R,
                                              const float* __restrict__ gam, const float* __restrict__ bet,
                                              float* __restrict__ oF, u16* __restrict__ oB) {
  __shared__ float red[8];
  const int row = blockIdx.x, t = threadIdx.x;
  const int wave = t >> 6, lane = t & 63;
  const size_t off = (size_t)row * 1024 + t * 4;
  f4 x = *(const f4*)(X + off);
  f4 r = *(const f4*)(R + off);
  float v[4];
#pragma unroll
  for (int j = 0; j < 4; ++j) v[j] = x[j] + r[j];
  if (X2) {
    f4 x2 = *(const f4*)(X2 + off);
#pragma unroll
    for (int j = 0; j < 4; ++j) v[j] += x2[j];
  }
  if (bias) {
    f4 bb = *(const f4*)(bias + t * 4);
#pragma unroll
    for (int j = 0; j < 4; ++j) v[j] += bb[j];
  }
  float s = 0.f, sq = 0.f;
#pragma unroll
  for (int j = 0; j < 4; ++j) { s += v[j]; sq += v[j] * v[j]; }
#pragma unroll
  for (int d = 1; d < 64; d <<= 1) {
    s += __shfl_xor(s, d, 64);
    sq += __shfl_xor(sq, d, 64);
  }
  if (lane == 0) { red[wave * 2] = s; red[wave * 2 + 1] = sq; }
  __syncthreads();
  s = red[0] + red[2] + red[4] + red[6];
  sq = red[1] + red[3] + red[5] + red[7];
  const float mu = s * (1.0f / 1024.0f);
  const float var = sq * (1.0f / 1024.0f) - mu * mu;
  const float rs = rsqrtf(var + 1e-5f);
  f4 g4 = *(const f4*)(gam + t * 4);
  f4 b4 = *(const f4*)(bet + t * 4);
  f4 y;
#pragma unroll
  for (int j = 0; j < 4; ++j) y[j] = (v[j] - mu) * rs * g4[j] + b4[j];
  *(f4*)(oF + off) = y;
  if (oB) {
    u16x4 yb;
#pragma unroll
    for (int j = 0; j < 4; ++j) yb[j] = f2bf(y[j]);
    *(u16x4*)(oB + off) = yb;
  }
}

// ---------------- launcher ----------------
extern "C" void kernel_launch(void* const* d_in, const int* in_sizes, int n_in,
                              void* d_out, int out_size, void* d_ws, size_t ws_size,
                              hipStream_t stream) {
  const float* embeds = (const float*)d_in[0];
  const float* enc = (const float*)d_in[1];
  const float* wq1 = (const float*)d_in[2];
  const float* wk1 = (const float*)d_in[3];
  const float* wv1 = (const float*)d_in[4];
  const float* wo1 = (const float*)d_in[5];
  const float* wq2 = (const float*)d_in[6];
  const float* wk2 = (const float*)d_in[7];
  const float* wv2 = (const float*)d_in[8];
  const float* wo2 = (const float*)d_in[9];
  const float* ln1g = (const float*)d_in[10];
  const float* ln1b = (const float*)d_in[11];
  const float* ln2g = (const float*)d_in[12];
  const float* ln2b = (const float*)d_in[13];
  const float* ln3g = (const float*)d_in[14];
  const float* ln3b = (const float*)d_in[15];
  const float* w1 = (const float*)d_in[16];
  const float* b1 = (const float*)d_in[17];
  const float* w2 = (const float*)d_in[18];
  const float* b2 = (const float*)d_in[19];
  float* out = (float*)d_out;
  char* ws = (char*)d_ws;
  const size_t MB = (size_t)1 << 20;

  u16* QKV = (u16*)(ws + 0 * MB);      // 48MB [8192, 3072] bf16
  u16* Vtb = (u16*)(ws + 48 * MB);     // 16MB
  u16* Hd = (u16*)(ws + 64 * MB);      // 16MB heads
  float* Of = (float*)(ws + 80 * MB);  // 32MB f32 gemm out (FF2: 64MB span, z=1 in 112-144)
  u16* ebf = (u16*)(ws + 112 * MB);    // 16MB (x1 bf16 later; dead by FF2)
  u16* encb = (u16*)(ws + 128 * MB);   // 16MB (x2 bf16 later; dead by FF2)
  float* x1f = (float*)(ws + 144 * MB);
  float* x2f = (float*)(ws + 176 * MB);
  u16* Wq1t = (u16*)(ws + 208 * MB);   // Wq1t/Wk1t/Wv1t contiguous = fused [3072,1024]
  u16* Wk1t = (u16*)(ws + 210 * MB);
  u16* Wv1t = (u16*)(ws + 212 * MB);
  u16* Wo1b = (u16*)(ws + 214 * MB);
  u16* Wq2t = (u16*)(ws + 216 * MB);
  u16* Wk2t = (u16*)(ws + 218 * MB);   // Wk2t/Wv2t contiguous = fused [2048,1024]
  u16* Wv2t = (u16*)(ws + 220 * MB);
  u16* Wo2b = (u16*)(ws + 222 * MB);
  u16* W1b = (u16*)(ws + 224 * MB);  // 8MB
  u16* W2b = (u16*)(ws + 232 * MB);  // 8MB, end = 240MB
  u16* x1b = ebf;
  u16* x2b = encb;
  u16* Hff = (u16*)(ws + 0 * MB);  // 64MB, reuses QKV/Vtb after attn2

  dim3 blk(256);

  cast_bf16<<<8192, blk, 0, stream>>>(embeds, ebf);
  cast_bf16<<<8192, blk, 0, stream>>>(enc, encb);
  cast_wqkv<<<dim3(16, 16), blk, 0, stream>>>(wq1, Wq1t);
  cast_wqkv<<<dim3(16, 16), blk, 0, stream>>>(wk1, Wk1t);
  cast_wqkv<<<dim3(16, 16), blk, 0, stream>>>(wv1, Wv1t);
  cast_wqkv<<<dim3(16, 16), blk, 0, stream>>>(wq2, Wq2t);
  cast_wqkv<<<dim3(16, 16), blk, 0, stream>>>(wk2, Wk2t);
  cast_wqkv<<<dim3(16, 16), blk, 0, stream>>>(wv2, Wv2t);
  cast_bf16<<<1024, blk, 0, stream>>>(wo1, Wo1b);
  cast_bf16<<<1024, blk, 0, stream>>>(wo2, Wo2b);
  cast_bf16<<<4096, blk, 0, stream>>>(w1, W1b);
  cast_bf16<<<4096, blk, 0, stream>>>(w2, W2b);

  // ---- masked self-attention + LN1 ----
  gemm8<5><<<dim3(12, 32, 1), 512, 0, stream>>>(ebf, 1024, Wq1t, 1024, QKV, 3072, nullptr, 1024, 0);
  transpose_v<<<dim3(32, 128), blk, 0, stream>>>(QKV, Vtb, 3072, 2048);
  flash_attn<1><<<dim3(8, 128), blk, 0, stream>>>(QKV, QKV + 1024, Vtb, Hd, 3072);
  gemm_bt<1><<<dim3(8, 64), blk, 0, stream>>>(Hd, Wo1b, Of, 1024, 1024, 1024);
  ln_res<<<8192, blk, 0, stream>>>(Of, nullptr, nullptr, embeds, ln1g, ln1b, x1f, x1b);

  // ---- cross-attention + LN2 ----
  gemm_bt<4><<<dim3(8, 64), blk, 0, stream>>>(x1b, Wq2t, QKV, 1024, 1024, 3072);
  gemm8<0><<<dim3(8, 32, 1), 512, 0, stream>>>(encb, 1024, Wk2t, 1024, QKV + 1024, 3072, nullptr, 1024, 0);
  transpose_v<<<dim3(32, 128), blk, 0, stream>>>(QKV, Vtb, 3072, 2048);
  flash_attn<0><<<dim3(8, 128), blk, 0, stream>>>(QKV, QKV + 1024, Vtb, Hd, 3072);
  gemm_bt<1><<<dim3(8, 64), blk, 0, stream>>>(Hd, Wo2b, Of, 1024, 1024, 1024);
  ln_res<<<8192, blk, 0, stream>>>(Of, nullptr, nullptr, x1f, ln2g, ln2b, x2f, x2b);

  // ---- feed-forward + LN3 ----
  gemm8<2><<<dim3(16, 32, 1), 512, 0, stream>>>(x2b, 1024, W1b, 1024, Hff, 4096, b1, 1024, 0);
  gemm8<1><<<dim3(4, 32, 2), 512, 0, stream>>>(Hff, 4096, W2b, 4096, Of, 1024, nullptr, 2048,
                                               (long long)8192 * 1024);
  ln_res<<<8192, blk, 0, stream>>>(Of, Of + (size_t)8192 * 1024, b2, x2f, ln3g, ln3b, out, nullptr);
}

// Round 8
// 719.466 us; speedup vs baseline: 1.3114x; 1.2128x over previous
//
#include <hip/hip_runtime.h>
#include <cstdint>
#include <cstddef>

typedef unsigned short u16;
typedef __attribute__((ext_vector_type(4))) float f32x4;
typedef __attribute__((ext_vector_type(4))) float f4;
typedef __attribute__((ext_vector_type(8))) short short8x;
typedef __attribute__((ext_vector_type(4))) u16 u16x4;
typedef __attribute__((ext_vector_type(8))) u16 u16x8;

#define DEV static __device__ __forceinline__

DEV void gl_lds16(const void* g, void* l) {
  __builtin_amdgcn_global_load_lds(
      (const __attribute__((address_space(1))) unsigned int*)g,
      (__attribute__((address_space(3))) unsigned int*)l, 16, 0, 0);
}

DEV u16 f2bf(float f) {
  unsigned u = __float_as_uint(f);
  u += 0x7fffu + ((u >> 16) & 1u);
  return (u16)(u >> 16);
}

// ---------------- cast / pack kernels ----------------

__global__ __launch_bounds__(256) void cast_bf16(const float* __restrict__ X, u16* __restrict__ Y) {
  size_t i = ((size_t)blockIdx.x * 256 + threadIdx.x) * 4;
  f4 v = *(const f4*)(X + i);
  u16x4 y;
#pragma unroll
  for (int j = 0; j < 4; ++j) y[j] = f2bf(v[j]);
  *(u16x4*)(Y + i) = y;
}

// wq [H,D,DH] f32 -> Wt [H*DH, D] bf16 (B^T form for x @ W)
__global__ __launch_bounds__(256) void cast_wqkv(const float* __restrict__ W, u16* __restrict__ Wt) {
  __shared__ float tile[64][65];
  const int t = threadIdx.x;
  const int h = blockIdx.y;
  const int d0 = blockIdx.x * 64;
  const float* Wb = W + (size_t)h * (1024 * 64);
  const int di = t >> 2;
  const int j0 = (t & 3) * 16;
#pragma unroll
  for (int c = 0; c < 4; ++c) {
    f4 v = *(const f4*)(Wb + (size_t)(d0 + di) * 64 + j0 + c * 4);
#pragma unroll
    for (int j = 0; j < 4; ++j) tile[di][j0 + c * 4 + j] = v[j];
  }
  __syncthreads();
  const int k = t >> 2;
  const int dd0 = (t & 3) * 16;
  u16x8 o0, o1;
#pragma unroll
  for (int u = 0; u < 8; ++u) o0[u] = f2bf(tile[dd0 + u][k]);
#pragma unroll
  for (int u = 0; u < 8; ++u) o1[u] = f2bf(tile[dd0 + 8 + u][k]);
  u16* dst = Wt + (size_t)(h * 64 + k) * 1024 + d0 + dd0;
  *(u16x8*)(dst) = o0;
  *(u16x8*)(dst + 8) = o1;
}

// V columns of QKV [B,S,QKVS] bf16 -> Vt [B*H, DH, S] bf16
__global__ __launch_bounds__(256) void transpose_v(const u16* __restrict__ V, u16* __restrict__ Vt,
                                                   int vstride, int voff) {
  __shared__ u16 tile[32][72];
  const int t = threadIdx.x;
  const int bh = blockIdx.y;
  const int s0 = blockIdx.x * 32;
  const u16* Vb = V + (size_t)(bh >> 4) * (1024 * (size_t)vstride) + voff + (bh & 15) * 64;
  const int si = t >> 3, d0 = (t & 7) * 8;
  u16x8 val = *(const u16x8*)(Vb + (size_t)(s0 + si) * vstride + d0);
#pragma unroll
  for (int u = 0; u < 8; ++u) tile[si][d0 + u] = val[u];
  __syncthreads();
  const int d = t >> 2, sj0 = (t & 3) * 8;
  u16x8 o;
#pragma unroll
  for (int u = 0; u < 8; ++u) o[u] = tile[sj0 + u][d];
  *(u16x8*)(Vt + (size_t)bh * (64 * 1024) + (size_t)d * 1024 + s0 + sj0) = o;
}

// ---------------- GEMM 128x128, BK=32, 2-phase, static ping-pong addressing ----------------
// C[M,N](ldc) = A[M,K] * Bt[N,K]^T.  M,N mult of 128; K mult of 64.
// EPI: 0=bf16, 1=f32, 2=bias+GELU->bf16, 3=bias->f32, 4=scale(1/8)->bf16,
//      5=fused QKV: scale cols<1024 by 1/8 -> bf16
template <int EPI>
__global__ __launch_bounds__(256, 3) void gemm_bt(const u16* __restrict__ A, const u16* __restrict__ Bt,
                                                  void* __restrict__ C, const float* __restrict__ bias,
                                                  int K, int ldc) {
  __shared__ u16 As0[128 * 32], Bs0[128 * 32];
  __shared__ u16 As1[128 * 32], Bs1[128 * 32];
  const int t = threadIdx.x;
  const int wave = t >> 6, lane = t & 63;
  const int lr = lane & 15, lkg = lane >> 4;
  const int swz = (lr >> 1) & 3;
  const int wr = (wave >> 1) * 64, wc = (wave & 1) * 64;

  // XCD-bijective block swizzle (all launch grids have nwg % 8 == 0)
  const int gx = gridDim.x;
  const int nwg = gx * gridDim.y;
  const int flat = blockIdx.y * gx + blockIdx.x;
  const int wg = (flat & 7) * (nwg >> 3) + (flat >> 3);
  const int m0 = (wg / gx) * 128, n0 = (wg % gx) * 128;

  // staging source pointers (advanced by +64B per BK=32 step)
  const int schunk = ((t & 3) ^ ((t >> 3) & 3)) << 4;
  const size_t rowskip = (size_t)64 * K * 2;
  const char* gA0 = (const char*)(A + (size_t)(m0 + (t >> 2)) * K) + schunk;
  const char* gA1 = gA0 + rowskip;
  const char* gB0 = (const char*)(Bt + (size_t)(n0 + (t >> 2)) * K) + schunk;
  const char* gB1 = gB0 + rowskip;

  // static LDS staging destinations (wave-uniform)
  char* dA0 = (char*)As0 + wave * 1024;
  char* dB0 = (char*)Bs0 + wave * 1024;
  char* dA1 = (char*)As1 + wave * 1024;
  char* dB1 = (char*)Bs1 + wave * 1024;

  // static LDS read bases (lane-constant); reads use +m*1024 immediate offsets
  const int aoff = (wr + lr) * 64 + ((lkg ^ swz) << 4);
  const int boff = (wc + lr) * 64 + ((lkg ^ swz) << 4);
  const char* rA0 = (const char*)As0 + aoff;
  const char* rB0 = (const char*)Bs0 + boff;
  const char* rA1 = (const char*)As1 + aoff;
  const char* rB1 = (const char*)Bs1 + boff;

  const f32x4 fzero = {0.f, 0.f, 0.f, 0.f};
  f32x4 acc[4][4];
#pragma unroll
  for (int m = 0; m < 4; ++m)
#pragma unroll
    for (int n = 0; n < 4; ++n) acc[m][n] = fzero;

  auto compute = [&](const char* rA, const char* rB) {
    short8x aF[4], bF[4];
#pragma unroll
    for (int m = 0; m < 4; ++m) aF[m] = *(const short8x*)(rA + m * 1024);
#pragma unroll
    for (int n = 0; n < 4; ++n) bF[n] = *(const short8x*)(rB + n * 1024);
#pragma unroll
    for (int m = 0; m < 4; ++m)
#pragma unroll
      for (int n = 0; n < 4; ++n)
        acc[m][n] = __builtin_amdgcn_mfma_f32_16x16x32_bf16(aF[m], bF[n], acc[m][n], 0, 0, 0);
  };

  // prologue: stage kt=0 -> buf0; advance pointers to kt=1
  gl_lds16(gA0, dA0); gl_lds16(gA1, dA0 + 4096);
  gl_lds16(gB0, dB0); gl_lds16(gB1, dB0 + 4096);
  gA0 += 64; gA1 += 64; gB0 += 64; gB1 += 64;
  __syncthreads();

  const int nk2 = K >> 6;  // pairs of BK=32 steps (K % 64 == 0)
  for (int p = 0; p < nk2; ++p) {
    // stage kt=2p+1 -> buf1 (always valid: 2p+1 <= nk-1)
    gl_lds16(gA0, dA1); gl_lds16(gA1, dA1 + 4096);
    gl_lds16(gB0, dB1); gl_lds16(gB1, dB1 + 4096);
    gA0 += 64; gA1 += 64; gB0 += 64; gB1 += 64;  // -> kt=2p+2
    compute(rA0, rB0);
    __syncthreads();
    // stage kt=2p+2 -> buf0
    if (p + 1 < nk2) {
      gl_lds16(gA0, dA0); gl_lds16(gA1, dA0 + 4096);
      gl_lds16(gB0, dB0); gl_lds16(gB1, dB0 + 4096);
    }
    gA0 += 64; gA1 += 64; gB0 += 64; gB1 += 64;  // -> kt=2p+3
    compute(rA1, rB1);
    __syncthreads();
  }

  // ---- epilogue ----
#pragma unroll
  for (int m = 0; m < 4; ++m) {
#pragma unroll
    for (int rr = 0; rr < 4; ++rr) {
      const int gm = m0 + wr + m * 16 + lkg * 4 + rr;
#pragma unroll
      for (int n = 0; n < 4; ++n) {
        const int gn = n0 + wc + n * 16 + lr;
        float v = acc[m][n][rr];
        if (EPI == 2 || EPI == 3) v += bias[gn];
        if (EPI == 2) v = 0.5f * v * (1.0f + erff(v * 0.70710678118654752f));
        if (EPI == 4) v *= 0.125f;
        if (EPI == 5 && gn < 1024) v *= 0.125f;
        if (EPI == 1 || EPI == 3)
          ((float*)C)[(size_t)gm * ldc + gn] = v;
        else
          ((u16*)C)[(size_t)gm * ldc + gn] = f2bf(v);
      }
    }
  }
}

// ---------------- flash attention (verified) ----------------
template <int CAUSAL>
__global__ __launch_bounds__(256, 2) void flash_attn(const u16* __restrict__ Q, const u16* __restrict__ Kk,
                                                     const u16* __restrict__ Vt, u16* __restrict__ O,
                                                     int qst) {
  __shared__ u16 Ks[2][64 * 64];
  __shared__ u16 Vs[2][64 * 64];
  __shared__ u16 Ps[4][32 * 72];
  const int t = threadIdx.x;
  const int wave = t >> 6, lane = t & 63;
  const int lr = lane & 15, lkg = lane >> 4, lk = lkg * 8;
  const int sw = lr & 7;
  const int bh = blockIdx.y;
  const size_t base = (size_t)(bh >> 4) * (1024 * (size_t)qst) + (bh & 15) * 64;
  const u16* Qb = Q + base;
  const u16* Kb = Kk + base;
  const u16* Vtb = Vt + (size_t)bh * (64 * 1024);
  u16* Ob = O + (size_t)(bh >> 4) * (1024 * 1024) + (bh & 15) * 64;
  const int qt = blockIdx.x * 128;
  const int qw = qt + wave * 32;

  const f32x4 fzero = {0.f, 0.f, 0.f, 0.f};
  short8x qf[2][2];
#pragma unroll
  for (int rb = 0; rb < 2; ++rb)
#pragma unroll
    for (int kk = 0; kk < 2; ++kk)
      qf[rb][kk] = *(const short8x*)(Qb + (size_t)(qw + rb * 16 + lr) * qst + kk * 32 + lk);

  float m_[2][4], l_[2][4];
  f32x4 o_[2][4];
#pragma unroll
  for (int rb = 0; rb < 2; ++rb) {
#pragma unroll
    for (int rr = 0; rr < 4; ++rr) { m_[rb][rr] = -1e30f; l_[rb][rr] = 0.f; }
#pragma unroll
    for (int db = 0; db < 4; ++db) o_[rb][db] = fzero;
  }

  const int rsel = lane >> 3;
  const int csw = ((lane & 7) ^ rsel) << 4;

  auto stage = [&](int buf, int kv0) {
#pragma unroll
    for (int s = 0; s < 2; ++s) {
      const int row = s * 32 + wave * 8 + rsel;
      gl_lds16((const char*)Kb + (size_t)(kv0 + row) * (size_t)(qst * 2) + csw,
               (char*)&Ks[buf][0] + s * 4096 + wave * 1024);
      gl_lds16((const char*)Vtb + (size_t)row * 2048 + (size_t)kv0 * 2 + csw,
               (char*)&Vs[buf][0] + s * 4096 + wave * 1024);
    }
  };

  const int kv_end = CAUSAL ? (qt + 128) : 1024;
  const int nt = kv_end >> 6;

  stage(0, 0);
  __syncthreads();
  int cur = 0;
  for (int tt = 0; tt < nt; ++tt) {
    const int kv0 = tt * 64;
    if (tt + 1 < nt) stage(cur ^ 1, kv0 + 64);

    const char* ksb = (const char*)&Ks[cur][0];
    const char* vsb = (const char*)&Vs[cur][0];

    short8x kf[4][2];
#pragma unroll
    for (int nb = 0; nb < 4; ++nb) {
      const int row = nb * 16 + lr;
#pragma unroll
      for (int kk = 0; kk < 2; ++kk)
        kf[nb][kk] = *(const short8x*)(ksb + row * 128 + (((kk * 4 + lkg) ^ sw) << 4));
    }

#pragma unroll
    for (int rb = 0; rb < 2; ++rb) {
      f32x4 s[4];
#pragma unroll
      for (int nb = 0; nb < 4; ++nb) {
        s[nb] = __builtin_amdgcn_mfma_f32_16x16x32_bf16(qf[rb][0], kf[nb][0], fzero, 0, 0, 0);
        s[nb] = __builtin_amdgcn_mfma_f32_16x16x32_bf16(qf[rb][1], kf[nb][1], s[nb], 0, 0, 0);
      }
      if (CAUSAL && (kv0 + 63 > qw + rb * 16)) {
#pragma unroll
        for (int rr = 0; rr < 4; ++rr) {
          const int qg = qw + rb * 16 + lkg * 4 + rr;
#pragma unroll
          for (int nb = 0; nb < 4; ++nb)
            if (kv0 + nb * 16 + lr > qg) s[nb][rr] = -1e30f;
        }
      }
#pragma unroll
      for (int rr = 0; rr < 4; ++rr) {
        float mx = fmaxf(fmaxf(s[0][rr], s[1][rr]), fmaxf(s[2][rr], s[3][rr]));
#pragma unroll
        for (int d = 1; d < 16; d <<= 1) mx = fmaxf(mx, __shfl_xor(mx, d, 16));
        const float mold = m_[rb][rr];
        const float mnew = fmaxf(mold, mx);
        float p[4];
#pragma unroll
        for (int nb = 0; nb < 4; ++nb) p[nb] = __expf(s[nb][rr] - mnew);
        float rsum = (p[0] + p[1]) + (p[2] + p[3]);
#pragma unroll
        for (int d = 1; d < 16; d <<= 1) rsum += __shfl_xor(rsum, d, 16);
        const float alpha = __expf(mold - mnew);
        m_[rb][rr] = mnew;
        l_[rb][rr] = l_[rb][rr] * alpha + rsum;
#pragma unroll
        for (int db = 0; db < 4; ++db) o_[rb][db][rr] *= alpha;
        const int prow = rb * 16 + lkg * 4 + rr;
#pragma unroll
        for (int nb = 0; nb < 4; ++nb)
          Ps[wave][prow * 72 + nb * 16 + lr] = f2bf(p[nb]);
      }
    }
    asm volatile("s_waitcnt lgkmcnt(0)" ::: "memory");

    short8x vF[4][2];
#pragma unroll
    for (int db = 0; db < 4; ++db) {
      const int row = db * 16 + lr;
#pragma unroll
      for (int kk = 0; kk < 2; ++kk)
        vF[db][kk] = *(const short8x*)(vsb + row * 128 + (((kk * 4 + lkg) ^ sw) << 4));
    }
#pragma unroll
    for (int rb = 0; rb < 2; ++rb) {
#pragma unroll
      for (int kk = 0; kk < 2; ++kk) {
        const short8x aP = *(const short8x*)((const char*)&Ps[wave][0] + (rb * 16 + lr) * 144 + kk * 64 + lkg * 16);
#pragma unroll
        for (int db = 0; db < 4; ++db)
          o_[rb][db] = __builtin_amdgcn_mfma_f32_16x16x32_bf16(aP, vF[db][kk], o_[rb][db], 0, 0, 0);
      }
    }
    __syncthreads();
    cur ^= 1;
  }

#pragma unroll
  for (int rb = 0; rb < 2; ++rb)
#pragma unroll
    for (int rr = 0; rr < 4; ++rr) {
      const float inv = 1.0f / l_[rb][rr];
      const int qg = qw + rb * 16 + lkg * 4 + rr;
#pragma unroll
      for (int db = 0; db < 4; ++db)
        Ob[(size_t)qg * 1024 + db * 16 + lr] = f2bf(o_[rb][db][rr] * inv);
    }
}

// ---------------- LayerNorm(X [+bias] + R) ----------------
__global__ __launch_bounds__(256) void ln_res(const float* __restrict__ X, const float* __restrict__ bias,
                                              const float* __restrict__ R,
                                              const float* __restrict__ gam, const float* __restrict__ bet,
                                              float* __restrict__ oF, u16* __restrict__ oB) {
  __shared__ float red[8];
  const int row = blockIdx.x, t = threadIdx.x;
  const int wave = t >> 6, lane = t & 63;
  const size_t off = (size_t)row * 1024 + t * 4;
  f4 x = *(const f4*)(X + off);
  f4 r = *(const f4*)(R + off);
  float v[4];
#pragma unroll
  for (int j = 0; j < 4; ++j) v[j] = x[j] + r[j];
  if (bias) {
    f4 bb = *(const f4*)(bias + t * 4);
#pragma unroll
    for (int j = 0; j < 4; ++j) v[j] += bb[j];
  }
  float s = 0.f, sq = 0.f;
#pragma unroll
  for (int j = 0; j < 4; ++j) { s += v[j]; sq += v[j] * v[j]; }
#pragma unroll
  for (int d = 1; d < 64; d <<= 1) {
    s += __shfl_xor(s, d, 64);
    sq += __shfl_xor(sq, d, 64);
  }
  if (lane == 0) { red[wave * 2] = s; red[wave * 2 + 1] = sq; }
  __syncthreads();
  s = red[0] + red[2] + red[4] + red[6];
  sq = red[1] + red[3] + red[5] + red[7];
  const float mu = s * (1.0f / 1024.0f);
  const float var = sq * (1.0f / 1024.0f) - mu * mu;
  const float rs = rsqrtf(var + 1e-5f);
  f4 g4 = *(const f4*)(gam + t * 4);
  f4 b4 = *(const f4*)(bet + t * 4);
  f4 y;
#pragma unroll
  for (int j = 0; j < 4; ++j) y[j] = (v[j] - mu) * rs * g4[j] + b4[j];
  *(f4*)(oF + off) = y;
  if (oB) {
    u16x4 yb;
#pragma unroll
    for (int j = 0; j < 4; ++j) yb[j] = f2bf(y[j]);
    *(u16x4*)(oB + off) = yb;
  }
}

// ---------------- launcher ----------------
extern "C" void kernel_launch(void* const* d_in, const int* in_sizes, int n_in,
                              void* d_out, int out_size, void* d_ws, size_t ws_size,
                              hipStream_t stream) {
  const float* embeds = (const float*)d_in[0];
  const float* enc = (const float*)d_in[1];
  const float* wq1 = (const float*)d_in[2];
  const float* wk1 = (const float*)d_in[3];
  const float* wv1 = (const float*)d_in[4];
  const float* wo1 = (const float*)d_in[5];
  const float* wq2 = (const float*)d_in[6];
  const float* wk2 = (const float*)d_in[7];
  const float* wv2 = (const float*)d_in[8];
  const float* wo2 = (const float*)d_in[9];
  const float* ln1g = (const float*)d_in[10];
  const float* ln1b = (const float*)d_in[11];
  const float* ln2g = (const float*)d_in[12];
  const float* ln2b = (const float*)d_in[13];
  const float* ln3g = (const float*)d_in[14];
  const float* ln3b = (const float*)d_in[15];
  const float* w1 = (const float*)d_in[16];
  const float* b1 = (const float*)d_in[17];
  const float* w2 = (const float*)d_in[18];
  const float* b2 = (const float*)d_in[19];
  float* out = (float*)d_out;
  char* ws = (char*)d_ws;
  const size_t MB = (size_t)1 << 20;

  u16* QKV = (u16*)(ws + 0 * MB);      // 48MB [8192, 3072] bf16
  u16* Vtb = (u16*)(ws + 48 * MB);     // 16MB
  u16* Hd = (u16*)(ws + 64 * MB);      // 16MB heads
  float* Of = (float*)(ws + 80 * MB);  // 32MB f32 gemm out
  u16* ebf = (u16*)(ws + 112 * MB);    // 16MB (x1 bf16 later)
  u16* encb = (u16*)(ws + 128 * MB);   // 16MB (x2 bf16 later)
  float* x1f = (float*)(ws + 144 * MB);
  float* x2f = (float*)(ws + 176 * MB);
  u16* Wq1t = (u16*)(ws + 208 * MB);   // Wq1t/Wk1t/Wv1t contiguous = fused [3072,1024]
  u16* Wk1t = (u16*)(ws + 210 * MB);
  u16* Wv1t = (u16*)(ws + 212 * MB);
  u16* Wo1b = (u16*)(ws + 214 * MB);
  u16* Wq2t = (u16*)(ws + 216 * MB);
  u16* Wk2t = (u16*)(ws + 218 * MB);   // Wk2t/Wv2t contiguous = fused [2048,1024]
  u16* Wv2t = (u16*)(ws + 220 * MB);
  u16* Wo2b = (u16*)(ws + 222 * MB);
  u16* W1b = (u16*)(ws + 224 * MB);  // 8MB
  u16* W2b = (u16*)(ws + 232 * MB);  // 8MB, end = 240MB
  u16* x1b = ebf;
  u16* x2b = encb;
  u16* Hff = (u16*)(ws + 0 * MB);  // 64MB, reuses QKV/Vtb after attn2

  dim3 blk(256);

  cast_bf16<<<8192, blk, 0, stream>>>(embeds, ebf);
  cast_bf16<<<8192, blk, 0, stream>>>(enc, encb);
  cast_wqkv<<<dim3(16, 16), blk, 0, stream>>>(wq1, Wq1t);
  cast_wqkv<<<dim3(16, 16), blk, 0, stream>>>(wk1, Wk1t);
  cast_wqkv<<<dim3(16, 16), blk, 0, stream>>>(wv1, Wv1t);
  cast_wqkv<<<dim3(16, 16), blk, 0, stream>>>(wq2, Wq2t);
  cast_wqkv<<<dim3(16, 16), blk, 0, stream>>>(wk2, Wk2t);
  cast_wqkv<<<dim3(16, 16), blk, 0, stream>>>(wv2, Wv2t);
  cast_bf16<<<1024, blk, 0, stream>>>(wo1, Wo1b);
  cast_bf16<<<1024, blk, 0, stream>>>(wo2, Wo2b);
  cast_bf16<<<4096, blk, 0, stream>>>(w1, W1b);
  cast_bf16<<<4096, blk, 0, stream>>>(w2, W2b);

  // ---- masked self-attention + LN1 ----
  gemm_bt<5><<<dim3(24, 64), blk, 0, stream>>>(ebf, Wq1t, QKV, nullptr, 1024, 3072);
  transpose_v<<<dim3(32, 128), blk, 0, stream>>>(QKV, Vtb, 3072, 2048);
  flash_attn<1><<<dim3(8, 128), blk, 0, stream>>>(QKV, QKV + 1024, Vtb, Hd, 3072);
  gemm_bt<1><<<dim3(8, 64), blk, 0, stream>>>(Hd, Wo1b, Of, nullptr, 1024, 1024);
  ln_res<<<8192, blk, 0, stream>>>(Of, nullptr, embeds, ln1g, ln1b, x1f, x1b);

  // ---- cross-attention + LN2 ----
  gemm_bt<4><<<dim3(8, 64), blk, 0, stream>>>(x1b, Wq2t, QKV, nullptr, 1024, 3072);
  gemm_bt<0><<<dim3(16, 64), blk, 0, stream>>>(encb, Wk2t, QKV + 1024, nullptr, 1024, 3072);
  transpose_v<<<dim3(32, 128), blk, 0, stream>>>(QKV, Vtb, 3072, 2048);
  flash_attn<0><<<dim3(8, 128), blk, 0, stream>>>(QKV, QKV + 1024, Vtb, Hd, 3072);
  gemm_bt<1><<<dim3(8, 64), blk, 0, stream>>>(Hd, Wo2b, Of, nullptr, 1024, 1024);
  ln_res<<<8192, blk, 0, stream>>>(Of, nullptr, x1f, ln2g, ln2b, x2f, x2b);

  // ---- feed-forward + LN3 ----
  gemm_bt<2><<<dim3(32, 64), blk, 0, stream>>>(x2b, W1b, Hff, b1, 1024, 4096);
  gemm_bt<3><<<dim3(8, 64), blk, 0, stream>>>(Hff, W2b, Of, b2, 4096, 1024);
  ln_res<<<8192, blk, 0, stream>>>(Of, nullptr, x2f, ln3g, ln3b, out, nullptr);
}